// Round 5
// baseline (834.001 us; speedup 1.0000x reference)
//
#include <hip/hip_runtime.h>
#include <hip/hip_bf16.h>

// Problem constants (fixed by setup_inputs)
#define BB 2
#define TT 2048
#define DD 1024
#define HH 16
#define HD 64
#define WIN 16
#define NG 128          // T / stride global tokens
#define QKVLD 3072      // 3*D row stride of qkv

typedef __bf16 bf16x8 __attribute__((ext_vector_type(8)));
typedef float f32x4 __attribute__((ext_vector_type(4)));

__device__ __forceinline__ unsigned short f2bf(float f) {
    union { float f; unsigned int i; } x; x.f = f;
    unsigned int r = x.i + 0x7FFFu + ((x.i >> 16) & 1u);
    return (unsigned short)(r >> 16);
}

// C = A(MxK) @ B(KxN). B fp32 row-major (weights), converted to bf16 during
// LDS staging. A fp32 (A_F32=true) or bf16 (false). Output fp32.
// MODE 0: no bias. MODE 1: + fp32 bias.
template<bool A_F32, int MODE>
__global__ __launch_bounds__(256) void gemm_kernel(
    const void* __restrict__ Ap,
    const float* __restrict__ Bf,
    float* __restrict__ Cp,
    const float* __restrict__ bias,
    int M, int N, int K)
{
    __shared__ __align__(16) unsigned short As[64][32];  // [m][k] bf16
    __shared__ __align__(16) unsigned short Bs[64][32];  // [n][k] bf16 (transposed)
    const int bm = blockIdx.y * 64;
    const int bn = blockIdx.x * 64;
    const int tid  = threadIdx.x;
    const int wave = tid >> 6;
    const int lane = tid & 63;
    const int lm   = lane & 15;
    const int quad = lane >> 4;

    f32x4 acc[4] = {{0.f,0.f,0.f,0.f},{0.f,0.f,0.f,0.f},{0.f,0.f,0.f,0.f},{0.f,0.f,0.f,0.f}};

    const int ar  = tid >> 2;        // 0..63  A row
    const int ac  = (tid & 3) * 8;   // k group (8 elems)
    const int bk  = tid >> 3;        // 0..31  B k-row
    const int bn8 = (tid & 7) * 8;   // n group (8 elems)

    for (int k0 = 0; k0 < K; k0 += 32) {
        __syncthreads();   // protect LDS from previous iteration's readers
        // ---- stage A tile: row bm+ar, k [k0+ac, +8) ----
        {
            union { uint4 v; unsigned short u[8]; } o;
            if constexpr (A_F32) {
                const float* A = (const float*)Ap;
                const float* src = A + (size_t)(bm + ar) * K + k0 + ac;
                float4 f0 = *(const float4*)(src);
                float4 f1 = *(const float4*)(src + 4);
                o.u[0] = f2bf(f0.x); o.u[1] = f2bf(f0.y);
                o.u[2] = f2bf(f0.z); o.u[3] = f2bf(f0.w);
                o.u[4] = f2bf(f1.x); o.u[5] = f2bf(f1.y);
                o.u[6] = f2bf(f1.z); o.u[7] = f2bf(f1.w);
            } else {
                const unsigned short* A = (const unsigned short*)Ap;
                o.v = *(const uint4*)(A + (size_t)(bm + ar) * K + k0 + ac);
            }
            *(uint4*)(&As[ar][ac]) = o.v;
        }
        // ---- stage B tile (transposed): k row k0+bk, n [bn+bn8, +8) ----
        {
            const float* src = Bf + (size_t)(k0 + bk) * N + bn + bn8;
            float4 f0 = *(const float4*)(src);
            float4 f1 = *(const float4*)(src + 4);
            Bs[bn8 + 0][bk] = f2bf(f0.x);
            Bs[bn8 + 1][bk] = f2bf(f0.y);
            Bs[bn8 + 2][bk] = f2bf(f0.z);
            Bs[bn8 + 3][bk] = f2bf(f0.w);
            Bs[bn8 + 4][bk] = f2bf(f1.x);
            Bs[bn8 + 5][bk] = f2bf(f1.y);
            Bs[bn8 + 6][bk] = f2bf(f1.z);
            Bs[bn8 + 7][bk] = f2bf(f1.w);
        }
        __syncthreads();
        bf16x8 a = *(const bf16x8*)(&As[wave * 16 + lm][quad * 8]);
        #pragma unroll
        for (int c = 0; c < 4; ++c) {
            bf16x8 b = *(const bf16x8*)(&Bs[c * 16 + lm][quad * 8]);
            acc[c] = __builtin_amdgcn_mfma_f32_16x16x32_bf16(a, b, acc[c], 0, 0, 0);
        }
    }

    #pragma unroll
    for (int c = 0; c < 4; ++c) {
        #pragma unroll
        for (int r = 0; r < 4; ++r) {
            const int row = bm + wave * 16 + quad * 4 + r;
            const int col = bn + c * 16 + lm;
            float v = acc[c][r];
            if constexpr (MODE == 1) v += bias[col];
            Cp[(size_t)row * N + col] = v;
        }
    }
}

// One wave per (b,h,t); lane = head dim. qkv fp32 rows: [q(1024)|k(1024)|v(1024)].
__global__ __launch_bounds__(256) void attn_kernel(
    const float* __restrict__ qkv,
    unsigned short* __restrict__ attn_out)    // (B*T) x D bf16
{
    const int wid  = (int)((blockIdx.x * blockDim.x + threadIdx.x) >> 6);
    const int lane = threadIdx.x & 63;
    const int t = wid & (TT - 1);
    const int h = (wid >> 11) & (HH - 1);
    const int b = wid >> 15;
    const float* base = qkv + (size_t)b * TT * QKVLD;
    const int hoff = h * HD + lane;
    const float q = base[(size_t)t * QKVLD + hoff];
    const float scale = 0.125f;   // 1/sqrt(64)

    // ---- local sliding window: keys t-15..t; padded slots have logit 0 ----
    float p[WIN];
    #pragma unroll
    for (int w = 0; w < WIN; ++w) {
        const int tk = t - (WIN - 1) + w;
        float prod = (tk >= 0) ? q * base[(size_t)tk * QKVLD + 1024 + hoff] : 0.f;
        #pragma unroll
        for (int m = 1; m < 64; m <<= 1) prod += __shfl_xor(prod, m, 64);
        p[w] = (tk >= 0) ? prod * scale : 0.f;   // padded logit == exactly 0
    }
    float mx = p[0];
    #pragma unroll
    for (int w = 1; w < WIN; ++w) mx = fmaxf(mx, p[w]);
    float l = 0.f;
    #pragma unroll
    for (int w = 0; w < WIN; ++w) { p[w] = __expf(p[w] - mx); l += p[w]; }
    float out_l = 0.f;
    #pragma unroll
    for (int w = 0; w < WIN; ++w) {
        const int tk = t - (WIN - 1) + w;
        if (tk >= 0) out_l += p[w] * base[(size_t)tk * QKVLD + 2048 + hoff];
    }
    out_l /= l;

    // ---- global tokens: 128 keys at t = 16*g, full (non-causal) softmax ----
    float s[8];
    #pragma unroll
    for (int j = 0; j < 8; ++j) {
        float prod = q * base[(size_t)(j * 16) * QKVLD + 1024 + hoff];
        #pragma unroll
        for (int m = 1; m < 64; m <<= 1) prod += __shfl_xor(prod, m, 64);
        s[j] = prod * scale;
    }
    float m2 = s[0];
    #pragma unroll
    for (int j = 1; j < 8; ++j) m2 = fmaxf(m2, s[j]);
    float l2 = 0.f, accv = 0.f;
    #pragma unroll
    for (int j = 0; j < 8; ++j) {
        const float pe = __expf(s[j] - m2);
        l2 += pe;
        accv += pe * base[(size_t)(j * 16) * QKVLD + 2048 + hoff];
    }
    for (int g0 = 8; g0 < NG; g0 += 8) {
        #pragma unroll
        for (int j = 0; j < 8; ++j) {
            float prod = q * base[(size_t)((g0 + j) * 16) * QKVLD + 1024 + hoff];
            #pragma unroll
            for (int m = 1; m < 64; m <<= 1) prod += __shfl_xor(prod, m, 64);
            s[j] = prod * scale;
        }
        float cm = s[0];
        #pragma unroll
        for (int j = 1; j < 8; ++j) cm = fmaxf(cm, s[j]);
        if (cm > m2) {
            const float alpha = __expf(m2 - cm);
            l2 *= alpha; accv *= alpha; m2 = cm;
        }
        #pragma unroll
        for (int j = 0; j < 8; ++j) {
            const float pe = __expf(s[j] - m2);
            l2 += pe;
            accv += pe * base[(size_t)((g0 + j) * 16) * QKVLD + 2048 + hoff];
        }
    }
    const float out_g = accv / l2;

    attn_out[(size_t)(b * TT + t) * DD + hoff] = f2bf(out_l + out_g);
}

extern "C" void kernel_launch(void* const* d_in, const int* in_sizes, int n_in,
                              void* d_out, int out_size, void* d_ws, size_t ws_size,
                              hipStream_t stream) {
    const float* x      = (const float*)d_in[0];  // (B*T) x D fp32
    const float* w_qkv  = (const float*)d_in[1];  // D x 3D fp32
    const float* w_proj = (const float*)d_in[2];  // D x D fp32
    const float* b_proj = (const float*)d_in[3];  // D fp32

    // ws layout (58.7 MB): qkv fp32 (4096 x 3072) | attnb bf16 (4096 x 1024)
    float* qkv = (float*)d_ws;
    unsigned short* attnb =
        (unsigned short*)((char*)d_ws + (size_t)4096 * 3072 * 4);
    float* out = (float*)d_out;   // fp32 — reference output dtype

    // 1) qkv = x @ w_qkv  (fp32 in/out, bf16 MFMA internally)
    gemm_kernel<true, 0><<<dim3(3072 / 64, 4096 / 64), 256, 0, stream>>>(
        x, w_qkv, qkv, nullptr, 4096, 3072, 1024);

    // 2) sparse attention (local window + global strided), bf16 out
    attn_kernel<<<(BB * HH * TT) / 4, 256, 0, stream>>>(qkv, attnb);

    // 3) out = attnb @ w_proj + b_proj, fp32 out
    gemm_kernel<false, 1><<<dim3(1024 / 64, 4096 / 64), 256, 0, stream>>>(
        attnb, w_proj, out, b_proj, 4096, 1024, 1024);
}

// Round 6
// 350.032 us; speedup vs baseline: 2.3826x; 2.3826x over previous
//
#include <hip/hip_runtime.h>
#include <hip/hip_bf16.h>

// Problem constants (fixed by setup_inputs)
#define BB 2
#define TT 2048
#define DD 1024
#define HH 16
#define HD 64
#define WIN 16
#define NG 128          // T / stride global tokens
#define QKVLD 3072      // 3*D row stride of qkv
#define TQ 128          // queries per attention block

typedef __bf16 bf16x8 __attribute__((ext_vector_type(8)));
typedef float f32x4 __attribute__((ext_vector_type(4)));
typedef _Float16 h2 __attribute__((ext_vector_type(2)));

__device__ __forceinline__ unsigned short f2bf(float f) {
    union { float f; unsigned int i; } x; x.f = f;
    unsigned int r = x.i + 0x7FFFu + ((x.i >> 16) & 1u);
    return (unsigned short)(r >> 16);
}
__device__ __forceinline__ unsigned short hbits(float f) {
    union { _Float16 h; unsigned short u; } x; x.h = (_Float16)f; return x.u;
}

#if defined(__has_builtin)
#  if __has_builtin(__builtin_amdgcn_fdot2)
#    define DOT2(a, b, c) __builtin_amdgcn_fdot2((a), (b), (c), false)
#  endif
#endif
#ifndef DOT2
#  define DOT2(a, b, c) ((c) + (float)(a).x * (float)(b).x + (float)(a).y * (float)(b).y)
#endif

// C = A(MxK) @ B(KxN). B fp32 row-major (weights), converted to bf16 during
// LDS staging. A fp32 (A_F32=true) or bf16 (false). Output fp32.
// MODE 0: no bias. MODE 1: + fp32 bias.
template<bool A_F32, int MODE>
__global__ __launch_bounds__(256) void gemm_kernel(
    const void* __restrict__ Ap,
    const float* __restrict__ Bf,
    float* __restrict__ Cp,
    const float* __restrict__ bias,
    int M, int N, int K)
{
    __shared__ __align__(16) unsigned short As[64][32];  // [m][k] bf16
    __shared__ __align__(16) unsigned short Bs[64][32];  // [n][k] bf16 (transposed)
    const int bm = blockIdx.y * 64;
    const int bn = blockIdx.x * 64;
    const int tid  = threadIdx.x;
    const int wave = tid >> 6;
    const int lane = tid & 63;
    const int lm   = lane & 15;
    const int quad = lane >> 4;

    f32x4 acc[4] = {{0.f,0.f,0.f,0.f},{0.f,0.f,0.f,0.f},{0.f,0.f,0.f,0.f},{0.f,0.f,0.f,0.f}};

    const int ar  = tid >> 2;        // 0..63  A row
    const int ac  = (tid & 3) * 8;   // k group (8 elems)
    const int bk  = tid >> 3;        // 0..31  B k-row
    const int bn8 = (tid & 7) * 8;   // n group (8 elems)

    for (int k0 = 0; k0 < K; k0 += 32) {
        __syncthreads();
        {
            union { uint4 v; unsigned short u[8]; } o;
            if constexpr (A_F32) {
                const float* A = (const float*)Ap;
                const float* src = A + (size_t)(bm + ar) * K + k0 + ac;
                float4 f0 = *(const float4*)(src);
                float4 f1 = *(const float4*)(src + 4);
                o.u[0] = f2bf(f0.x); o.u[1] = f2bf(f0.y);
                o.u[2] = f2bf(f0.z); o.u[3] = f2bf(f0.w);
                o.u[4] = f2bf(f1.x); o.u[5] = f2bf(f1.y);
                o.u[6] = f2bf(f1.z); o.u[7] = f2bf(f1.w);
            } else {
                const unsigned short* A = (const unsigned short*)Ap;
                o.v = *(const uint4*)(A + (size_t)(bm + ar) * K + k0 + ac);
            }
            *(uint4*)(&As[ar][ac]) = o.v;
        }
        {
            const float* src = Bf + (size_t)(k0 + bk) * N + bn + bn8;
            float4 f0 = *(const float4*)(src);
            float4 f1 = *(const float4*)(src + 4);
            Bs[bn8 + 0][bk] = f2bf(f0.x);
            Bs[bn8 + 1][bk] = f2bf(f0.y);
            Bs[bn8 + 2][bk] = f2bf(f0.z);
            Bs[bn8 + 3][bk] = f2bf(f0.w);
            Bs[bn8 + 4][bk] = f2bf(f1.x);
            Bs[bn8 + 5][bk] = f2bf(f1.y);
            Bs[bn8 + 6][bk] = f2bf(f1.z);
            Bs[bn8 + 7][bk] = f2bf(f1.w);
        }
        __syncthreads();
        bf16x8 a = *(const bf16x8*)(&As[wave * 16 + lm][quad * 8]);
        #pragma unroll
        for (int c = 0; c < 4; ++c) {
            bf16x8 b = *(const bf16x8*)(&Bs[c * 16 + lm][quad * 8]);
            acc[c] = __builtin_amdgcn_mfma_f32_16x16x32_bf16(a, b, acc[c], 0, 0, 0);
        }
    }

    #pragma unroll
    for (int c = 0; c < 4; ++c) {
        #pragma unroll
        for (int r = 0; r < 4; ++r) {
            const int row = bm + wave * 16 + quad * 4 + r;
            const int col = bn + c * 16 + lm;
            float v = acc[c][r];
            if constexpr (MODE == 1) v += bias[col];
            Cp[(size_t)row * N + col] = v;
        }
    }
}

// Sparse attention, restructured: block = 256 threads = 128 queries x 2 halves
// for one (b,h). K/V staged in LDS as fp16; scores via v_dot2_f32_f16; no
// cross-lane shuffles in hot loops (only scalar pair-merges + final merge).
__global__ __launch_bounds__(256) void attn_kernel(
    const float* __restrict__ qkv,
    unsigned short* __restrict__ attn_out)    // (B*T) x D bf16
{
    __shared__ __align__(16) unsigned short smem[19584];  // 38.25 KB, phases alias
    unsigned short* Kl = smem;            // local K  [144][68] fp16
    unsigned short* Vl = smem + 9792;     // local V  [144][68]
    unsigned short* Kg = smem;            // global K [128][64]
    unsigned short* Vg = smem + 8192;     // global V [128][64]

    const int tid  = threadIdx.x;
    const int bx   = blockIdx.x;          // 512 blocks
    const int bh   = bx >> 4;
    const int t0   = (bx & 15) * TQ;
    const int b    = bh >> 4;
    const int h    = bh & 15;
    const int qloc = tid >> 1;            // 0..127
    const int hf   = tid & 1;             // key-half
    const int tq   = t0 + qloc;

    // ---- load scaled query into 32 packed-half regs ----
    h2 qh[32];
    {
        const float* qrow = qkv + (size_t)(b * TT + tq) * QKVLD + h * HD;
        #pragma unroll
        for (int i = 0; i < 16; ++i) {
            float4 f = *(const float4*)(qrow + i * 4);
            h2 a, c;
            a.x = (_Float16)(f.x * 0.125f); a.y = (_Float16)(f.y * 0.125f);
            c.x = (_Float16)(f.z * 0.125f); c.y = (_Float16)(f.w * 0.125f);
            qh[2 * i] = a; qh[2 * i + 1] = c;
        }
    }

    float out[HD];
    #pragma unroll
    for (int d = 0; d < HD; ++d) out[d] = 0.f;

    // ================= LOCAL phase =================
    // stage rows t = t0-15 .. t0+127 (143 rows); zero-fill t<0 (exact
    // reference semantics: zero K row -> logit 0; zero V row -> no contrib)
    for (int rr = tid >> 1; rr < 143; rr += 128) {
        const int t  = t0 + rr - 15;
        const int d0 = hf * 32;
        unsigned short* kd = Kl + rr * 68 + d0;
        unsigned short* vd = Vl + rr * 68 + d0;
        if (t < 0) {
            ushort4 z = {0, 0, 0, 0};
            #pragma unroll
            for (int j = 0; j < 8; ++j) { *(ushort4*)(kd + j * 4) = z; *(ushort4*)(vd + j * 4) = z; }
        } else {
            const float* kr = qkv + (size_t)(b * TT + t) * QKVLD + 1024 + h * HD + d0;
            const float* vr = kr + 1024;
            #pragma unroll
            for (int j = 0; j < 8; ++j) {
                float4 fk = *(const float4*)(kr + j * 4);
                float4 fv = *(const float4*)(vr + j * 4);
                ushort4 uk = { hbits(fk.x), hbits(fk.y), hbits(fk.z), hbits(fk.w) };
                ushort4 uv = { hbits(fv.x), hbits(fv.y), hbits(fv.z), hbits(fv.w) };
                *(ushort4*)(kd + j * 4) = uk;
                *(ushort4*)(vd + j * 4) = uv;
            }
        }
    }
    __syncthreads();

    auto score_l = [&](int rr) -> float {
        const unsigned short* kp = Kl + rr * 68;
        float s0 = 0.f, s1 = 0.f, s2 = 0.f, s3 = 0.f;
        #pragma unroll
        for (int c = 0; c < 8; ++c) {
            union { uint2 u; h2 hh[2]; } A, B;
            A.u = *(const uint2*)(kp + c * 8);
            B.u = *(const uint2*)(kp + c * 8 + 4);
            s0 = DOT2(A.hh[0], qh[4 * c + 0], s0);
            s1 = DOT2(A.hh[1], qh[4 * c + 1], s1);
            s2 = DOT2(B.hh[0], qh[4 * c + 2], s2);
            s3 = DOT2(B.hh[1], qh[4 * c + 3], s3);
        }
        return (s0 + s1) + (s2 + s3);
    };

    // pass A: online (m,l) over my 8 window keys
    float m1 = -1e30f, l1 = 0.f;
    #pragma unroll
    for (int j = 0; j < 8; ++j) {
        float s  = score_l(qloc + hf * 8 + j);
        float nm = fmaxf(m1, s);
        l1 = l1 * __expf(m1 - nm) + __expf(s - nm);
        m1 = nm;
    }
    {   // pair merge (other 8 keys)
        float mo = __shfl_xor(m1, 1, 64);
        float lo = __shfl_xor(l1, 1, 64);
        float M  = fmaxf(m1, mo);
        l1 = l1 * __expf(m1 - M) + lo * __expf(mo - M);
        m1 = M;
    }
    const float inv1 = 1.f / l1;
    // pass B: accumulate my 8 keys' p*v (normalized) into out
    #pragma unroll 2
    for (int j = 0; j < 8; ++j) {
        const int rr = qloc + hf * 8 + j;
        float p = __expf(score_l(rr) - m1) * inv1;
        const unsigned short* vp = Vl + rr * 68;
        #pragma unroll
        for (int c = 0; c < 16; ++c) {
            union { uint2 u; h2 hh[2]; } U;
            U.u = *(const uint2*)(vp + c * 4);
            out[4 * c + 0] += p * (float)U.hh[0].x;
            out[4 * c + 1] += p * (float)U.hh[0].y;
            out[4 * c + 2] += p * (float)U.hh[1].x;
            out[4 * c + 3] += p * (float)U.hh[1].y;
        }
    }
    __syncthreads();

    // ================= GLOBAL phase =================
    {   // stage 128 global keys (t = 16g)
        const int g  = tid >> 1;
        const int d0 = hf * 32;
        const float* kr = qkv + (size_t)(b * TT + g * 16) * QKVLD + 1024 + h * HD + d0;
        const float* vr = kr + 1024;
        unsigned short* kd = Kg + g * 64 + d0;
        unsigned short* vd = Vg + g * 64 + d0;
        #pragma unroll
        for (int j = 0; j < 8; ++j) {
            float4 fk = *(const float4*)(kr + j * 4);
            float4 fv = *(const float4*)(vr + j * 4);
            ushort4 uk = { hbits(fk.x), hbits(fk.y), hbits(fk.z), hbits(fk.w) };
            ushort4 uv = { hbits(fv.x), hbits(fv.y), hbits(fv.z), hbits(fv.w) };
            *(ushort4*)(kd + j * 4) = uk;
            *(ushort4*)(vd + j * 4) = uv;
        }
    }
    __syncthreads();

    auto score_g = [&](int g) -> float {
        const unsigned short* kp = Kg + g * 64;
        float s0 = 0.f, s1 = 0.f, s2 = 0.f, s3 = 0.f;
        #pragma unroll
        for (int c = 0; c < 8; ++c) {
            union { uint4 u; h2 hh[4]; } U;
            U.u = *(const uint4*)(kp + c * 8);
            s0 = DOT2(U.hh[0], qh[4 * c + 0], s0);
            s1 = DOT2(U.hh[1], qh[4 * c + 1], s1);
            s2 = DOT2(U.hh[2], qh[4 * c + 2], s2);
            s3 = DOT2(U.hh[3], qh[4 * c + 3], s3);
        }
        return (s0 + s1) + (s2 + s3);
    };

    // pass A: online (m,l) over my 64 global keys
    float m2 = -1e30f, l2 = 0.f;
    #pragma unroll 2
    for (int gg = 0; gg < 64; ++gg) {
        float s  = score_g(hf * 64 + gg);
        float nm = fmaxf(m2, s);
        l2 = l2 * __expf(m2 - nm) + __expf(s - nm);
        m2 = nm;
    }
    {   // pair merge (other 64 keys)
        float mo = __shfl_xor(m2, 1, 64);
        float lo = __shfl_xor(l2, 1, 64);
        float M  = fmaxf(m2, mo);
        l2 = l2 * __expf(m2 - M) + lo * __expf(mo - M);
        m2 = M;
    }
    const float inv2 = 1.f / l2;
    // pass B: accumulate my 64 keys' p*v (normalized) into out
    #pragma unroll 2
    for (int gg = 0; gg < 64; ++gg) {
        const int g = hf * 64 + gg;
        float p = __expf(score_g(g) - m2) * inv2;
        const unsigned short* vp = Vg + g * 64;
        #pragma unroll
        for (int c = 0; c < 8; ++c) {
            union { uint4 u; h2 hh[4]; } U;
            U.u = *(const uint4*)(vp + c * 8);
            out[8 * c + 0] += p * (float)U.hh[0].x;
            out[8 * c + 1] += p * (float)U.hh[0].y;
            out[8 * c + 2] += p * (float)U.hh[1].x;
            out[8 * c + 3] += p * (float)U.hh[1].y;
            out[8 * c + 4] += p * (float)U.hh[2].x;
            out[8 * c + 5] += p * (float)U.hh[2].y;
            out[8 * c + 6] += p * (float)U.hh[3].x;
            out[8 * c + 7] += p * (float)U.hh[3].y;
        }
    }

    // ---- final pair merge (partner holds the other halves' partial sums) ----
    const size_t ob = (size_t)(b * TT + tq) * DD + h * HD;
    #pragma unroll
    for (int dp = 0; dp < 32; ++dp) {
        float v0 = out[2 * dp]     + __shfl_xor(out[2 * dp],     1, 64);
        float v1 = out[2 * dp + 1] + __shfl_xor(out[2 * dp + 1], 1, 64);
        if ((dp >> 4) == hf) {
            unsigned int pk = (unsigned int)f2bf(v0) | ((unsigned int)f2bf(v1) << 16);
            *(unsigned int*)(attn_out + ob + 2 * dp) = pk;
        }
    }
}

extern "C" void kernel_launch(void* const* d_in, const int* in_sizes, int n_in,
                              void* d_out, int out_size, void* d_ws, size_t ws_size,
                              hipStream_t stream) {
    const float* x      = (const float*)d_in[0];  // (B*T) x D fp32
    const float* w_qkv  = (const float*)d_in[1];  // D x 3D fp32
    const float* w_proj = (const float*)d_in[2];  // D x D fp32
    const float* b_proj = (const float*)d_in[3];  // D fp32

    // ws layout (58.7 MB): qkv fp32 (4096 x 3072) | attnb bf16 (4096 x 1024)
    float* qkv = (float*)d_ws;
    unsigned short* attnb =
        (unsigned short*)((char*)d_ws + (size_t)4096 * 3072 * 4);
    float* out = (float*)d_out;

    // 1) qkv = x @ w_qkv  (fp32 in/out, bf16 MFMA internally)
    gemm_kernel<true, 0><<<dim3(3072 / 64, 4096 / 64), 256, 0, stream>>>(
        x, w_qkv, qkv, nullptr, 4096, 3072, 1024);

    // 2) sparse attention (local window + global strided), bf16 out
    attn_kernel<<<dim3(32 * (TT / TQ)), 256, 0, stream>>>(qkv, attnb);

    // 3) out = attnb @ w_proj + b_proj, fp32 out
    gemm_kernel<false, 1><<<dim3(1024 / 64, 4096 / 64), 256, 0, stream>>>(
        attnb, w_proj, out, b_proj, 4096, 1024, 1024);
}

// Round 7
// 237.502 us; speedup vs baseline: 3.5115x; 1.4738x over previous
//
#include <hip/hip_runtime.h>
#include <hip/hip_bf16.h>

// Problem constants (fixed by setup_inputs)
#define BB 2
#define TT 2048
#define DD 1024
#define HH 16
#define HD 64
#define WIN 16
#define NG 128          // T / stride global tokens
#define QKVLD 3072      // 3*D row stride of qkv
#define TQ 128          // queries per attention block

typedef __bf16 bf16x8 __attribute__((ext_vector_type(8)));
typedef float f32x4 __attribute__((ext_vector_type(4)));
typedef _Float16 h2 __attribute__((ext_vector_type(2)));

__device__ __forceinline__ unsigned short f2bf(float f) {
    union { float f; unsigned int i; } x; x.f = f;
    unsigned int r = x.i + 0x7FFFu + ((x.i >> 16) & 1u);
    return (unsigned short)(r >> 16);
}
__device__ __forceinline__ unsigned short f2h(float f) {
    union { _Float16 h; unsigned short u; } x; x.h = (_Float16)f; return x.u;
}

#if defined(__has_builtin)
#  if __has_builtin(__builtin_amdgcn_fdot2)
#    define DOT2(a, b, c) __builtin_amdgcn_fdot2((a), (b), (c), false)
#  endif
#endif
#ifndef DOT2
#  define DOT2(a, b, c) ((c) + (float)(a).x * (float)(b).x + (float)(a).y * (float)(b).y)
#endif

// async global->LDS, 16 B per lane; LDS dest = wave-uniform base + lane*16
__device__ __forceinline__ void gll16(const unsigned short* g, unsigned short* l) {
    __builtin_amdgcn_global_load_lds(
        (const __attribute__((address_space(1))) void*)g,
        (__attribute__((address_space(3))) void*)l,
        16, 0, 0);
}

// ---------------- pre-pass: fp32 -> bf16 flat convert (8 elems/thread) ----
__global__ __launch_bounds__(256) void conv_bf16_kernel(
    const float* __restrict__ in, unsigned short* __restrict__ out)
{
    const size_t i = ((size_t)blockIdx.x * 256 + threadIdx.x) * 8;
    float4 f0 = *(const float4*)(in + i);
    float4 f1 = *(const float4*)(in + i + 4);
    ushort4 a = { f2bf(f0.x), f2bf(f0.y), f2bf(f0.z), f2bf(f0.w) };
    ushort4 b = { f2bf(f1.x), f2bf(f1.y), f2bf(f1.z), f2bf(f1.w) };
    *(ushort4*)(out + i) = a;
    *(ushort4*)(out + i + 4) = b;
}

// ---------------- pre-pass: w (KxN fp32) -> wT (NxK bf16) ----------------
__global__ __launch_bounds__(256) void transpose_bf16_kernel(
    const float* __restrict__ w, unsigned short* __restrict__ wT, int K, int N)
{
    __shared__ float tile[32][33];
    const int n0 = blockIdx.x * 32, k0 = blockIdx.y * 32;
    const int tx = threadIdx.x & 31, ty = threadIdx.x >> 5;
    #pragma unroll
    for (int i = 0; i < 4; ++i)
        tile[ty + 8 * i][tx] = w[(size_t)(k0 + ty + 8 * i) * N + n0 + tx];
    __syncthreads();
    #pragma unroll
    for (int i = 0; i < 4; ++i)
        wT[(size_t)(n0 + ty + 8 * i) * K + k0 + tx] = f2bf(tile[tx][ty + 8 * i]);
}

// ---------------- m97-style GEMM: C = A(MxK) @ Bt(NxK)^T ------------------
// A, Bt bf16 row-major. 128x128 tile, BK=32, global_load_lds(16B) staging,
// 4 waves each computing 64x64 via 4x4 16x16x32 MFMA fragments.
// MODE 0: fp16 out, no bias. MODE 1: fp32 out + fp32 bias.
template<int MODE>
__global__ __launch_bounds__(256) void gemm_kernel(
    const unsigned short* __restrict__ A,
    const unsigned short* __restrict__ Bt,
    void* __restrict__ Cp,
    const float* __restrict__ bias,
    int M, int N, int K)
{
    __shared__ __align__(16) unsigned short As[128 * 32];
    __shared__ __align__(16) unsigned short Bs[128 * 32];
    const int tid  = threadIdx.x;
    const int wave = tid >> 6;
    const int lane = tid & 63;
    const int lm   = lane & 15;
    const int quad = lane >> 4;
    const int wm   = (wave >> 1) * 64;   // wave tile row offset
    const int wn   = (wave & 1) * 64;    // wave tile col offset
    const int bm   = blockIdx.y * 128;
    const int bn   = blockIdx.x * 128;

    f32x4 acc[4][4];
    const f32x4 z4 = { 0.f, 0.f, 0.f, 0.f };
    #pragma unroll
    for (int i = 0; i < 4; ++i)
        #pragma unroll
        for (int j = 0; j < 4; ++j) acc[i][j] = z4;

    // staging: wave w covers tile rows [w*32, w*32+32) via two 16-row loads;
    // per lane: row = lane/4, col = (lane&3)*8 within the 16-row group
    const int lrow = lane >> 2, lcol = (lane & 3) * 8;
    const unsigned short* gA0 = A  + (size_t)(bm + wave * 32 + lrow) * K + lcol;
    const unsigned short* gA1 = gA0 + (size_t)16 * K;
    const unsigned short* gB0 = Bt + (size_t)(bn + wave * 32 + lrow) * K + lcol;
    const unsigned short* gB1 = gB0 + (size_t)16 * K;
    unsigned short* lA0 = &As[(wave * 32) * 32];
    unsigned short* lA1 = &As[(wave * 32 + 16) * 32];
    unsigned short* lB0 = &Bs[(wave * 32) * 32];
    unsigned short* lB1 = &Bs[(wave * 32 + 16) * 32];

    for (int k0 = 0; k0 < K; k0 += 32) {
        __syncthreads();              // previous iteration's readers done
        gll16(gA0 + k0, lA0);
        gll16(gA1 + k0, lA1);
        gll16(gB0 + k0, lB0);
        gll16(gB1 + k0, lB1);
        __syncthreads();              // staged data visible (vmcnt drained)
        bf16x8 af[4], bfr[4];
        #pragma unroll
        for (int i = 0; i < 4; ++i)
            af[i] = *(const bf16x8*)&As[(wm + i * 16 + lm) * 32 + quad * 8];
        #pragma unroll
        for (int j = 0; j < 4; ++j)
            bfr[j] = *(const bf16x8*)&Bs[(wn + j * 16 + lm) * 32 + quad * 8];
        #pragma unroll
        for (int i = 0; i < 4; ++i)
            #pragma unroll
            for (int j = 0; j < 4; ++j)
                acc[i][j] = __builtin_amdgcn_mfma_f32_16x16x32_bf16(
                    af[i], bfr[j], acc[i][j], 0, 0, 0);
    }

    #pragma unroll
    for (int i = 0; i < 4; ++i) {
        #pragma unroll
        for (int r = 0; r < 4; ++r) {
            const int row = bm + wm + i * 16 + quad * 4 + r;
            #pragma unroll
            for (int j = 0; j < 4; ++j) {
                const int col = bn + wn + j * 16 + lm;
                float v = acc[i][j][r];
                if constexpr (MODE == 0) {
                    ((unsigned short*)Cp)[(size_t)row * N + col] = f2h(v);
                } else {
                    ((float*)Cp)[(size_t)row * N + col] = v + bias[col];
                }
            }
        }
    }
}

// Sparse attention: block = 256 threads = 128 queries x 2 key-halves for one
// (b,h). qkv is fp16; K/V staged in LDS via raw 16B copies; v_dot2 scores.
__global__ __launch_bounds__(256) void attn_kernel(
    const unsigned short* __restrict__ qkv,   // fp16 (B*T) x 3072
    unsigned short* __restrict__ attn_out)    // (B*T) x D bf16
{
    __shared__ __align__(16) unsigned short smem[19584];  // 38.25 KB, phases alias
    unsigned short* Kl = smem;            // local K  [144][68] fp16
    unsigned short* Vl = smem + 9792;     // local V  [144][68]
    unsigned short* Kg = smem;            // global K [128][64]
    unsigned short* Vg = smem + 8192;     // global V [128][64]

    const int tid  = threadIdx.x;
    const int bx   = blockIdx.x;          // 512 blocks
    const int bh   = bx >> 4;
    const int t0   = (bx & 15) * TQ;
    const int b    = bh >> 4;
    const int h    = bh & 15;
    const int qloc = tid >> 1;            // 0..127
    const int hf   = tid & 1;             // key-half
    const int tq   = t0 + qloc;

    // ---- load scaled query into 32 packed-half regs (0.125 = pow2, exact) ----
    h2 qh[32];
    {
        const unsigned short* qrow = qkv + (size_t)(b * TT + tq) * QKVLD + h * HD;
        const h2 sc = { (_Float16)0.125f, (_Float16)0.125f };
        #pragma unroll
        for (int i = 0; i < 8; ++i) {
            union { uint4 u; h2 hh[4]; } U;
            U.u = *(const uint4*)(qrow + i * 8);
            qh[4 * i + 0] = U.hh[0] * sc;
            qh[4 * i + 1] = U.hh[1] * sc;
            qh[4 * i + 2] = U.hh[2] * sc;
            qh[4 * i + 3] = U.hh[3] * sc;
        }
    }

    float out[HD];
    #pragma unroll
    for (int d = 0; d < HD; ++d) out[d] = 0.f;

    // ================= LOCAL phase =================
    for (int rr = tid >> 1; rr < 143; rr += 128) {
        const int t  = t0 + rr - 15;
        const int d0 = hf * 32;
        unsigned short* kd = Kl + rr * 68 + d0;
        unsigned short* vd = Vl + rr * 68 + d0;
        if (t < 0) {
            uint4 zz = { 0, 0, 0, 0 };
            #pragma unroll
            for (int j = 0; j < 4; ++j) { *(uint4*)(kd + j * 8) = zz; *(uint4*)(vd + j * 8) = zz; }
        } else {
            const unsigned short* kr = qkv + (size_t)(b * TT + t) * QKVLD + 1024 + h * HD + d0;
            const unsigned short* vr = kr + 1024;
            #pragma unroll
            for (int j = 0; j < 4; ++j) {
                *(uint4*)(kd + j * 8) = *(const uint4*)(kr + j * 8);
                *(uint4*)(vd + j * 8) = *(const uint4*)(vr + j * 8);
            }
        }
    }
    __syncthreads();

    auto score_l = [&](int rr) -> float {
        const unsigned short* kp = Kl + rr * 68;
        float s0 = 0.f, s1 = 0.f, s2 = 0.f, s3 = 0.f;
        #pragma unroll
        for (int c = 0; c < 8; ++c) {
            union { uint2 u; h2 hh[2]; } A, B;
            A.u = *(const uint2*)(kp + c * 8);
            B.u = *(const uint2*)(kp + c * 8 + 4);
            s0 = DOT2(A.hh[0], qh[4 * c + 0], s0);
            s1 = DOT2(A.hh[1], qh[4 * c + 1], s1);
            s2 = DOT2(B.hh[0], qh[4 * c + 2], s2);
            s3 = DOT2(B.hh[1], qh[4 * c + 3], s3);
        }
        return (s0 + s1) + (s2 + s3);
    };

    float m1 = -1e30f, l1 = 0.f;
    #pragma unroll
    for (int j = 0; j < 8; ++j) {
        float s  = score_l(qloc + hf * 8 + j);
        float nm = fmaxf(m1, s);
        l1 = l1 * __expf(m1 - nm) + __expf(s - nm);
        m1 = nm;
    }
    {
        float mo = __shfl_xor(m1, 1, 64);
        float lo = __shfl_xor(l1, 1, 64);
        float M  = fmaxf(m1, mo);
        l1 = l1 * __expf(m1 - M) + lo * __expf(mo - M);
        m1 = M;
    }
    const float inv1 = 1.f / l1;
    #pragma unroll 2
    for (int j = 0; j < 8; ++j) {
        const int rr = qloc + hf * 8 + j;
        float p = __expf(score_l(rr) - m1) * inv1;
        const unsigned short* vp = Vl + rr * 68;
        #pragma unroll
        for (int c = 0; c < 16; ++c) {
            union { uint2 u; h2 hh[2]; } U;
            U.u = *(const uint2*)(vp + c * 4);
            out[4 * c + 0] += p * (float)U.hh[0].x;
            out[4 * c + 1] += p * (float)U.hh[0].y;
            out[4 * c + 2] += p * (float)U.hh[1].x;
            out[4 * c + 3] += p * (float)U.hh[1].y;
        }
    }
    __syncthreads();

    // ================= GLOBAL phase =================
    {
        const int g  = tid >> 1;
        const int d0 = hf * 32;
        const unsigned short* kr = qkv + (size_t)(b * TT + g * 16) * QKVLD + 1024 + h * HD + d0;
        const unsigned short* vr = kr + 1024;
        unsigned short* kd = Kg + g * 64 + d0;
        unsigned short* vd = Vg + g * 64 + d0;
        #pragma unroll
        for (int j = 0; j < 4; ++j) {
            *(uint4*)(kd + j * 8) = *(const uint4*)(kr + j * 8);
            *(uint4*)(vd + j * 8) = *(const uint4*)(vr + j * 8);
        }
    }
    __syncthreads();

    auto score_g = [&](int g) -> float {
        const unsigned short* kp = Kg + g * 64;
        float s0 = 0.f, s1 = 0.f, s2 = 0.f, s3 = 0.f;
        #pragma unroll
        for (int c = 0; c < 8; ++c) {
            union { uint4 u; h2 hh[4]; } U;
            U.u = *(const uint4*)(kp + c * 8);
            s0 = DOT2(U.hh[0], qh[4 * c + 0], s0);
            s1 = DOT2(U.hh[1], qh[4 * c + 1], s1);
            s2 = DOT2(U.hh[2], qh[4 * c + 2], s2);
            s3 = DOT2(U.hh[3], qh[4 * c + 3], s3);
        }
        return (s0 + s1) + (s2 + s3);
    };

    float m2 = -1e30f, l2 = 0.f;
    #pragma unroll 2
    for (int gg = 0; gg < 64; ++gg) {
        float s  = score_g(hf * 64 + gg);
        float nm = fmaxf(m2, s);
        l2 = l2 * __expf(m2 - nm) + __expf(s - nm);
        m2 = nm;
    }
    {
        float mo = __shfl_xor(m2, 1, 64);
        float lo = __shfl_xor(l2, 1, 64);
        float M  = fmaxf(m2, mo);
        l2 = l2 * __expf(m2 - M) + lo * __expf(mo - M);
        m2 = M;
    }
    const float inv2 = 1.f / l2;
    #pragma unroll 2
    for (int gg = 0; gg < 64; ++gg) {
        const int g = hf * 64 + gg;
        float p = __expf(score_g(g) - m2) * inv2;
        const unsigned short* vp = Vg + g * 64;
        #pragma unroll
        for (int c = 0; c < 8; ++c) {
            union { uint4 u; h2 hh[4]; } U;
            U.u = *(const uint4*)(vp + c * 8);
            out[8 * c + 0] += p * (float)U.hh[0].x;
            out[8 * c + 1] += p * (float)U.hh[0].y;
            out[8 * c + 2] += p * (float)U.hh[1].x;
            out[8 * c + 3] += p * (float)U.hh[1].y;
            out[8 * c + 4] += p * (float)U.hh[2].x;
            out[8 * c + 5] += p * (float)U.hh[2].y;
            out[8 * c + 6] += p * (float)U.hh[3].x;
            out[8 * c + 7] += p * (float)U.hh[3].y;
        }
    }

    const size_t ob = (size_t)(b * TT + tq) * DD + h * HD;
    #pragma unroll
    for (int dp = 0; dp < 32; ++dp) {
        float v0 = out[2 * dp]     + __shfl_xor(out[2 * dp],     1, 64);
        float v1 = out[2 * dp + 1] + __shfl_xor(out[2 * dp + 1], 1, 64);
        if ((dp >> 4) == hf) {
            unsigned int pk = (unsigned int)f2bf(v0) | ((unsigned int)f2bf(v1) << 16);
            *(unsigned int*)(attn_out + ob + 2 * dp) = pk;
        }
    }
}

extern "C" void kernel_launch(void* const* d_in, const int* in_sizes, int n_in,
                              void* d_out, int out_size, void* d_ws, size_t ws_size,
                              hipStream_t stream) {
    const float* x      = (const float*)d_in[0];  // (B*T) x D fp32
    const float* w_qkv  = (const float*)d_in[1];  // D x 3D fp32
    const float* w_proj = (const float*)d_in[2];  // D x D fp32
    const float* b_proj = (const float*)d_in[3];  // D fp32

    // ws layout (41.94 MB total):
    //   qkv fp16 (4096x3072)      : 25.166 MB
    //   xb/attnb bf16 (4096x1024) :  8.389 MB  (aliased: xb dead after gemm1)
    //   wqkvT bf16 (3072x1024)    :  6.291 MB
    //   wprojT bf16 (1024x1024)   :  2.097 MB
    char* ws = (char*)d_ws;
    unsigned short* qkv    = (unsigned short*)ws;
    unsigned short* xb     = (unsigned short*)(ws + 25165824);
    unsigned short* attnb  = xb;
    unsigned short* wqkvT  = (unsigned short*)(ws + 25165824 + 8388608);
    unsigned short* wprojT = (unsigned short*)(ws + 25165824 + 8388608 + 6291456);
    float* out = (float*)d_out;

    // 0) pre-convert: x -> bf16; weights -> transposed bf16
    conv_bf16_kernel<<<(4096 * 1024) / (256 * 8), 256, 0, stream>>>(x, xb);
    transpose_bf16_kernel<<<dim3(3072 / 32, 1024 / 32), 256, 0, stream>>>(
        w_qkv, wqkvT, 1024, 3072);
    transpose_bf16_kernel<<<dim3(1024 / 32, 1024 / 32), 256, 0, stream>>>(
        w_proj, wprojT, 1024, 1024);

    // 1) qkv = x @ w_qkv  (bf16 MFMA, fp16 out)
    gemm_kernel<0><<<dim3(3072 / 128, 4096 / 128), 256, 0, stream>>>(
        xb, wqkvT, qkv, nullptr, 4096, 3072, 1024);

    // 2) sparse attention (local window + global strided), bf16 out
    attn_kernel<<<dim3(32 * (TT / TQ)), 256, 0, stream>>>(qkv, attnb);

    // 3) out = attnb @ w_proj + b_proj, fp32 out
    gemm_kernel<1><<<dim3(1024 / 128, 4096 / 128), 256, 0, stream>>>(
        attnb, wprojT, out, b_proj, 4096, 1024, 1024);
}

// Round 8
// 228.946 us; speedup vs baseline: 3.6428x; 1.0374x over previous
//
#include <hip/hip_runtime.h>
#include <hip/hip_bf16.h>

// Problem constants (fixed by setup_inputs)
#define BB 2
#define TT 2048
#define DD 1024
#define HH 16
#define HD 64
#define WIN 16
#define NG 128          // T / stride global tokens
#define QKVLD 3072      // 3*D row stride of qkv

typedef __bf16 bf16x8 __attribute__((ext_vector_type(8)));
typedef float f32x4 __attribute__((ext_vector_type(4)));
typedef _Float16 h2 __attribute__((ext_vector_type(2)));

__device__ __forceinline__ unsigned short f2bf(float f) {
    union { float f; unsigned int i; } x; x.f = f;
    unsigned int r = x.i + 0x7FFFu + ((x.i >> 16) & 1u);
    return (unsigned short)(r >> 16);
}
__device__ __forceinline__ unsigned short f2h(float f) {
    union { _Float16 h; unsigned short u; } x; x.h = (_Float16)f; return x.u;
}

#if defined(__has_builtin)
#  if __has_builtin(__builtin_amdgcn_fdot2)
#    define DOT2(a, b, c) __builtin_amdgcn_fdot2((a), (b), (c), false)
#  endif
#endif
#ifndef DOT2
#  define DOT2(a, b, c) ((c) + (float)(a).x * (float)(b).x + (float)(a).y * (float)(b).y)
#endif

// async global->LDS, 16 B per lane; LDS dest = wave-uniform base + lane*16
__device__ __forceinline__ void gll16(const unsigned short* g, unsigned short* l) {
    __builtin_amdgcn_global_load_lds(
        (const __attribute__((address_space(1))) void*)g,
        (__attribute__((address_space(3))) void*)l,
        16, 0, 0);
}

// ---------------- pre-pass: fp32 -> bf16 flat convert (8 elems/thread) ----
__global__ __launch_bounds__(256) void conv_bf16_kernel(
    const float* __restrict__ in, unsigned short* __restrict__ out)
{
    const size_t i = ((size_t)blockIdx.x * 256 + threadIdx.x) * 8;
    float4 f0 = *(const float4*)(in + i);
    float4 f1 = *(const float4*)(in + i + 4);
    ushort4 a = { f2bf(f0.x), f2bf(f0.y), f2bf(f0.z), f2bf(f0.w) };
    ushort4 b = { f2bf(f1.x), f2bf(f1.y), f2bf(f1.z), f2bf(f1.w) };
    *(ushort4*)(out + i) = a;
    *(ushort4*)(out + i + 4) = b;
}

// ---------------- pre-pass: w (KxN fp32) -> wT (NxK bf16) ----------------
__global__ __launch_bounds__(256) void transpose_bf16_kernel(
    const float* __restrict__ w, unsigned short* __restrict__ wT, int K, int N)
{
    __shared__ float tile[32][33];
    const int n0 = blockIdx.x * 32, k0 = blockIdx.y * 32;
    const int tx = threadIdx.x & 31, ty = threadIdx.x >> 5;
    #pragma unroll
    for (int i = 0; i < 4; ++i)
        tile[ty + 8 * i][tx] = w[(size_t)(k0 + ty + 8 * i) * N + n0 + tx];
    __syncthreads();
    #pragma unroll
    for (int i = 0; i < 4; ++i)
        wT[(size_t)(n0 + ty + 8 * i) * K + k0 + tx] = f2bf(tile[tx][ty + 8 * i]);
}

// ---------------- m97-style GEMM: C = A(MxK) @ Bt(NxK)^T ------------------
// A, Bt bf16 row-major. 128x128 tile, BK=32, global_load_lds(16B) staging,
// 4 waves each computing 64x64 via 4x4 16x16x32 MFMA fragments.
// MODE 0: fp16 out, no bias. MODE 1: fp32 out + fp32 bias.
template<int MODE>
__global__ __launch_bounds__(256) void gemm_kernel(
    const unsigned short* __restrict__ A,
    const unsigned short* __restrict__ Bt,
    void* __restrict__ Cp,
    const float* __restrict__ bias,
    int M, int N, int K)
{
    __shared__ __align__(16) unsigned short As[128 * 32];
    __shared__ __align__(16) unsigned short Bs[128 * 32];
    const int tid  = threadIdx.x;
    const int wave = tid >> 6;
    const int lane = tid & 63;
    const int lm   = lane & 15;
    const int quad = lane >> 4;
    const int wm   = (wave >> 1) * 64;   // wave tile row offset
    const int wn   = (wave & 1) * 64;    // wave tile col offset
    const int bm   = blockIdx.y * 128;
    const int bn   = blockIdx.x * 128;

    f32x4 acc[4][4];
    const f32x4 z4 = { 0.f, 0.f, 0.f, 0.f };
    #pragma unroll
    for (int i = 0; i < 4; ++i)
        #pragma unroll
        for (int j = 0; j < 4; ++j) acc[i][j] = z4;

    const int lrow = lane >> 2, lcol = (lane & 3) * 8;
    const unsigned short* gA0 = A  + (size_t)(bm + wave * 32 + lrow) * K + lcol;
    const unsigned short* gA1 = gA0 + (size_t)16 * K;
    const unsigned short* gB0 = Bt + (size_t)(bn + wave * 32 + lrow) * K + lcol;
    const unsigned short* gB1 = gB0 + (size_t)16 * K;
    unsigned short* lA0 = &As[(wave * 32) * 32];
    unsigned short* lA1 = &As[(wave * 32 + 16) * 32];
    unsigned short* lB0 = &Bs[(wave * 32) * 32];
    unsigned short* lB1 = &Bs[(wave * 32 + 16) * 32];

    for (int k0 = 0; k0 < K; k0 += 32) {
        __syncthreads();
        gll16(gA0 + k0, lA0);
        gll16(gA1 + k0, lA1);
        gll16(gB0 + k0, lB0);
        gll16(gB1 + k0, lB1);
        __syncthreads();
        bf16x8 af[4], bfr[4];
        #pragma unroll
        for (int i = 0; i < 4; ++i)
            af[i] = *(const bf16x8*)&As[(wm + i * 16 + lm) * 32 + quad * 8];
        #pragma unroll
        for (int j = 0; j < 4; ++j)
            bfr[j] = *(const bf16x8*)&Bs[(wn + j * 16 + lm) * 32 + quad * 8];
        #pragma unroll
        for (int i = 0; i < 4; ++i)
            #pragma unroll
            for (int j = 0; j < 4; ++j)
                acc[i][j] = __builtin_amdgcn_mfma_f32_16x16x32_bf16(
                    af[i], bfr[j], acc[i][j], 0, 0, 0);
    }

    #pragma unroll
    for (int i = 0; i < 4; ++i) {
        #pragma unroll
        for (int r = 0; r < 4; ++r) {
            const int row = bm + wm + i * 16 + quad * 4 + r;
            #pragma unroll
            for (int j = 0; j < 4; ++j) {
                const int col = bn + wn + j * 16 + lm;
                float v = acc[i][j][r];
                if constexpr (MODE == 0) {
                    ((unsigned short*)Cp)[(size_t)row * N + col] = f2h(v);
                } else {
                    ((float*)Cp)[(size_t)row * N + col] = v + bias[col];
                }
            }
        }
    }
}

// Sparse attention v3: block = 256 threads = 32 queries x 8 key-splits for
// one (b, h, 32-query chunk). Grid = 2*16*64 = 2048 blocks.
// Single-pass softmax (no max subtraction: |s| <~ 10 << 88, softmax is
// shift-invariant). Scores kept in regs; weights normalized BEFORE pv so the
// packed-fp16 accumulator cannot overflow. LDS rows stride 72 halves (144 B,
// 16B-aligned b128); global-K rows swizzled so the 8 ks-lanes read banks 8
// apart (free 2-way); qloc lanes broadcast.
__global__ __launch_bounds__(256) void attn_kernel(
    const unsigned short* __restrict__ qkv,   // fp16 (B*T) x 3072
    unsigned short* __restrict__ attn_out)    // (B*T) x D bf16
{
    __shared__ __align__(16) unsigned short smem[72 * (2 * 128 + 2 * 47)];  // 50400 B
    unsigned short* Kg = smem;                   // [128][72] swizzled rows
    unsigned short* Vg = smem + 128 * 72;        // [128][72] swizzled rows
    unsigned short* Kl = smem + 2 * 128 * 72;    // [47][72]
    unsigned short* Vl = Kl + 47 * 72;

    const int tid   = threadIdx.x;
    const int bx    = blockIdx.x;
    const int chunk = bx & 63;
    const int bh    = bx >> 6;
    const int b     = bh >> 4;
    const int h     = bh & 15;
    const int t0    = chunk * 32;
    const int qloc  = tid >> 3;       // 0..31
    const int ks    = tid & 7;        // 0..7
    const int tq    = t0 + qloc;

    const size_t rowK = (size_t)(b * TT) * QKVLD + 1024 + h * HD;

    // ---- stage global K/V (swizzled rows) + local K/V ----
    {
        const int r = tid >> 1, hfi = tid & 1;
        const int g = ((r & 15) << 3) | (r >> 4);   // inverse row swizzle
        const unsigned short* kr = qkv + rowK + (size_t)g * 16 * QKVLD + hfi * 32;
        const unsigned short* vr = kr + 1024;
        unsigned short* kd = Kg + r * 72 + hfi * 32;
        unsigned short* vd = Vg + r * 72 + hfi * 32;
        #pragma unroll
        for (int j = 0; j < 4; ++j) {
            *(uint4*)(kd + j * 8) = *(const uint4*)(kr + j * 8);
            *(uint4*)(vd + j * 8) = *(const uint4*)(vr + j * 8);
        }
        if (r < 47) {
            const int t = t0 + r - 15;
            unsigned short* kld = Kl + r * 72 + hfi * 32;
            unsigned short* vld = Vl + r * 72 + hfi * 32;
            if (t < 0) {   // zero rows: logit 0 + no V contribution (= reference pad)
                uint4 z = { 0, 0, 0, 0 };
                #pragma unroll
                for (int j = 0; j < 4; ++j) { *(uint4*)(kld + j * 8) = z; *(uint4*)(vld + j * 8) = z; }
            } else {
                const unsigned short* klr = qkv + rowK + (size_t)t * QKVLD + hfi * 32;
                const unsigned short* vlr = klr + 1024;
                #pragma unroll
                for (int j = 0; j < 4; ++j) {
                    *(uint4*)(kld + j * 8) = *(const uint4*)(klr + j * 8);
                    *(uint4*)(vld + j * 8) = *(const uint4*)(vlr + j * 8);
                }
            }
        }
    }

    // ---- load scaled q (0.125 = pow2, exact in fp16) ----
    h2 qh[32];
    {
        const unsigned short* qrow = qkv + (size_t)(b * TT + tq) * QKVLD + h * HD;
        const h2 sc = { (_Float16)0.125f, (_Float16)0.125f };
        #pragma unroll
        for (int i = 0; i < 8; ++i) {
            union { uint4 u; h2 hh[4]; } U;
            U.u = *(const uint4*)(qrow + i * 8);
            qh[4 * i + 0] = U.hh[0] * sc; qh[4 * i + 1] = U.hh[1] * sc;
            qh[4 * i + 2] = U.hh[2] * sc; qh[4 * i + 3] = U.hh[3] * sc;
        }
    }

    __syncthreads();

    auto score = [&](const unsigned short* kp) -> float {
        float s0 = 0.f, s1 = 0.f, s2 = 0.f, s3 = 0.f;
        #pragma unroll
        for (int c = 0; c < 8; ++c) {
            union { uint4 u; h2 hh[4]; } U;
            U.u = *(const uint4*)(kp + c * 8);
            s0 = DOT2(U.hh[0], qh[4 * c + 0], s0);
            s1 = DOT2(U.hh[1], qh[4 * c + 1], s1);
            s2 = DOT2(U.hh[2], qh[4 * c + 2], s2);
            s3 = DOT2(U.hh[3], qh[4 * c + 3], s3);
        }
        return (s0 + s1) + (s2 + s3);
    };

    h2 out2[32];
    #pragma unroll
    for (int i = 0; i < 32; ++i) out2[i] = (h2){ (_Float16)0.f, (_Float16)0.f };

    // ---- local phase: my 2 window keys w = 2ks, 2ks+1 (rows qloc+w) ----
    float pl0 = __expf(score(Kl + (qloc + 2 * ks + 0) * 72));
    float pl1 = __expf(score(Kl + (qloc + 2 * ks + 1) * 72));
    float den = pl0 + pl1;
    den += __shfl_xor(den, 1, 64);
    den += __shfl_xor(den, 2, 64);
    den += __shfl_xor(den, 4, 64);
    const float inv = 1.f / den;
    #pragma unroll
    for (int w = 0; w < 2; ++w) {
        const float pn = (w ? pl1 : pl0) * inv;
        h2 ph; ph.x = (_Float16)pn; ph.y = ph.x;
        const unsigned short* vp = Vl + (qloc + 2 * ks + w) * 72;
        #pragma unroll
        for (int c = 0; c < 8; ++c) {
            union { uint4 u; h2 hh[4]; } U;
            U.u = *(const uint4*)(vp + c * 8);
            out2[4 * c + 0] += ph * U.hh[0]; out2[4 * c + 1] += ph * U.hh[1];
            out2[4 * c + 2] += ph * U.hh[2]; out2[4 * c + 3] += ph * U.hh[3];
        }
    }

    // ---- global phase: my 16 keys g = ks*16 + i ----
    float pg[16];
    float deng = 0.f;
    #pragma unroll 4
    for (int i = 0; i < 16; ++i) {
        const int g = ks * 16 + i;
        const int row = ((g & 7) << 4) | (g >> 3);
        const float e = __expf(score(Kg + row * 72));
        pg[i] = e; deng += e;
    }
    deng += __shfl_xor(deng, 1, 64);
    deng += __shfl_xor(deng, 2, 64);
    deng += __shfl_xor(deng, 4, 64);
    const float invg = 1.f / deng;
    #pragma unroll 4
    for (int i = 0; i < 16; ++i) {
        const int g = ks * 16 + i;
        const int row = ((g & 7) << 4) | (g >> 3);
        const float pn = pg[i] * invg;
        h2 ph; ph.x = (_Float16)pn; ph.y = ph.x;
        const unsigned short* vp = Vg + row * 72;
        #pragma unroll
        for (int c = 0; c < 8; ++c) {
            union { uint4 u; h2 hh[4]; } U;
            U.u = *(const uint4*)(vp + c * 8);
            out2[4 * c + 0] += ph * U.hh[0]; out2[4 * c + 1] += ph * U.hh[1];
            out2[4 * c + 2] += ph * U.hh[2]; out2[4 * c + 3] += ph * U.hh[3];
        }
    }

    // ---- reduce over ks (in-wave xor 1,2,4) ----
    #pragma unroll
    for (int m = 1; m <= 4; m <<= 1) {
        #pragma unroll
        for (int i = 0; i < 32; ++i) {
            union { h2 h; int v; } X; X.h = out2[i];
            X.v = __shfl_xor(X.v, m, 64);
            out2[i] += X.h;
        }
    }

    // ---- write my 8 dims [ks*8, ks*8+8) as bf16 ----
    {
        unsigned int pk[4];
        #pragma unroll
        for (int j = 0; j < 4; ++j) {
            h2 v = out2[ks * 4 + j];
            pk[j] = (unsigned int)f2bf((float)v.x) | ((unsigned int)f2bf((float)v.y) << 16);
        }
        uint4 st = { pk[0], pk[1], pk[2], pk[3] };
        *(uint4*)(attn_out + (size_t)(b * TT + tq) * DD + h * HD + ks * 8) = st;
    }
}

extern "C" void kernel_launch(void* const* d_in, const int* in_sizes, int n_in,
                              void* d_out, int out_size, void* d_ws, size_t ws_size,
                              hipStream_t stream) {
    const float* x      = (const float*)d_in[0];  // (B*T) x D fp32
    const float* w_qkv  = (const float*)d_in[1];  // D x 3D fp32
    const float* w_proj = (const float*)d_in[2];  // D x D fp32
    const float* b_proj = (const float*)d_in[3];  // D fp32

    // ws layout (41.94 MB total):
    //   qkv fp16 (4096x3072)      : 25.166 MB
    //   xb/attnb bf16 (4096x1024) :  8.389 MB  (aliased: xb dead after gemm1)
    //   wqkvT bf16 (3072x1024)    :  6.291 MB
    //   wprojT bf16 (1024x1024)   :  2.097 MB
    char* ws = (char*)d_ws;
    unsigned short* qkv    = (unsigned short*)ws;
    unsigned short* xb     = (unsigned short*)(ws + 25165824);
    unsigned short* attnb  = xb;
    unsigned short* wqkvT  = (unsigned short*)(ws + 25165824 + 8388608);
    unsigned short* wprojT = (unsigned short*)(ws + 25165824 + 8388608 + 6291456);
    float* out = (float*)d_out;

    // 0) pre-convert: x -> bf16; weights -> transposed bf16
    conv_bf16_kernel<<<(4096 * 1024) / (256 * 8), 256, 0, stream>>>(x, xb);
    transpose_bf16_kernel<<<dim3(3072 / 32, 1024 / 32), 256, 0, stream>>>(
        w_qkv, wqkvT, 1024, 3072);
    transpose_bf16_kernel<<<dim3(1024 / 32, 1024 / 32), 256, 0, stream>>>(
        w_proj, wprojT, 1024, 1024);

    // 1) qkv = x @ w_qkv  (bf16 MFMA, fp16 out)
    gemm_kernel<0><<<dim3(3072 / 128, 4096 / 128), 256, 0, stream>>>(
        xb, wqkvT, qkv, nullptr, 4096, 3072, 1024);

    // 2) sparse attention (local window + global strided), bf16 out
    attn_kernel<<<dim3(BB * HH * (TT / 32)), 256, 0, stream>>>(qkv, attnb);

    // 3) out = attnb @ w_proj + b_proj, fp32 out
    gemm_kernel<1><<<dim3(1024 / 128, 4096 / 128), 256, 0, stream>>>(
        attnb, wprojT, out, b_proj, 4096, 1024, 1024);
}

// Round 9
// 186.852 us; speedup vs baseline: 4.4634x; 1.2253x over previous
//
#include <hip/hip_runtime.h>
#include <hip/hip_bf16.h>

// Problem constants (fixed by setup_inputs)
#define BB 2
#define TT 2048
#define DD 1024
#define HH 16
#define HD 64
#define WIN 16
#define NG 128          // T / stride global tokens
#define QKVLD 3072      // 3*D row stride of qkv

typedef __bf16 bf16x8 __attribute__((ext_vector_type(8)));
typedef float f32x4 __attribute__((ext_vector_type(4)));
typedef _Float16 h2 __attribute__((ext_vector_type(2)));

__device__ __forceinline__ unsigned short f2bf(float f) {
    union { float f; unsigned int i; } x; x.f = f;
    unsigned int r = x.i + 0x7FFFu + ((x.i >> 16) & 1u);
    return (unsigned short)(r >> 16);
}
__device__ __forceinline__ unsigned short f2h(float f) {
    union { _Float16 h; unsigned short u; } x; x.h = (_Float16)f; return x.u;
}
__device__ __forceinline__ h2 shfl_h2(h2 v, int mask) {
    union { h2 h; int i; } X; X.h = v;
    X.i = __shfl_xor(X.i, mask, 64);
    return X.h;
}

#if defined(__has_builtin)
#  if __has_builtin(__builtin_amdgcn_fdot2)
#    define DOT2(a, b, c) __builtin_amdgcn_fdot2((a), (b), (c), false)
#  endif
#endif
#ifndef DOT2
#  define DOT2(a, b, c) ((c) + (float)(a).x * (float)(b).x + (float)(a).y * (float)(b).y)
#endif

// async global->LDS, 16 B per lane; LDS dest = wave-uniform base + lane*16
__device__ __forceinline__ void gll16(const unsigned short* g, unsigned short* l) {
    __builtin_amdgcn_global_load_lds(
        (const __attribute__((address_space(1))) void*)g,
        (__attribute__((address_space(3))) void*)l,
        16, 0, 0);
}

// ---------------- pre-pass: fp32 -> bf16 flat convert (8 elems/thread) ----
__global__ __launch_bounds__(256) void conv_bf16_kernel(
    const float* __restrict__ in, unsigned short* __restrict__ out)
{
    const size_t i = ((size_t)blockIdx.x * 256 + threadIdx.x) * 8;
    float4 f0 = *(const float4*)(in + i);
    float4 f1 = *(const float4*)(in + i + 4);
    ushort4 a = { f2bf(f0.x), f2bf(f0.y), f2bf(f0.z), f2bf(f0.w) };
    ushort4 b = { f2bf(f1.x), f2bf(f1.y), f2bf(f1.z), f2bf(f1.w) };
    *(ushort4*)(out + i) = a;
    *(ushort4*)(out + i + 4) = b;
}

// ---------------- pre-pass: w (KxN fp32) -> wT (NxK bf16) ----------------
__global__ __launch_bounds__(256) void transpose_bf16_kernel(
    const float* __restrict__ w, unsigned short* __restrict__ wT, int K, int N)
{
    __shared__ float tile[32][33];
    const int n0 = blockIdx.x * 32, k0 = blockIdx.y * 32;
    const int tx = threadIdx.x & 31, ty = threadIdx.x >> 5;
    #pragma unroll
    for (int i = 0; i < 4; ++i)
        tile[ty + 8 * i][tx] = w[(size_t)(k0 + ty + 8 * i) * N + n0 + tx];
    __syncthreads();
    #pragma unroll
    for (int i = 0; i < 4; ++i)
        wT[(size_t)(n0 + ty + 8 * i) * K + k0 + tx] = f2bf(tile[tx][ty + 8 * i]);
}

// ---------------- m97-style GEMM: C = A(MxK) @ Bt(NxK)^T ------------------
// A, Bt bf16 row-major. 128x128 tile, BK=32, global_load_lds(16B) staging,
// 4 waves each computing 64x64 via 4x4 16x16x32 MFMA fragments.
// MODE 0: fp16 out, no bias. MODE 1: fp32 out + fp32 bias.
template<int MODE>
__global__ __launch_bounds__(256) void gemm_kernel(
    const unsigned short* __restrict__ A,
    const unsigned short* __restrict__ Bt,
    void* __restrict__ Cp,
    const float* __restrict__ bias,
    int M, int N, int K)
{
    __shared__ __align__(16) unsigned short As[128 * 32];
    __shared__ __align__(16) unsigned short Bs[128 * 32];
    const int tid  = threadIdx.x;
    const int wave = tid >> 6;
    const int lane = tid & 63;
    const int lm   = lane & 15;
    const int quad = lane >> 4;
    const int wm   = (wave >> 1) * 64;   // wave tile row offset
    const int wn   = (wave & 1) * 64;    // wave tile col offset
    const int bm   = blockIdx.y * 128;
    const int bn   = blockIdx.x * 128;

    f32x4 acc[4][4];
    const f32x4 z4 = { 0.f, 0.f, 0.f, 0.f };
    #pragma unroll
    for (int i = 0; i < 4; ++i)
        #pragma unroll
        for (int j = 0; j < 4; ++j) acc[i][j] = z4;

    const int lrow = lane >> 2, lcol = (lane & 3) * 8;
    const unsigned short* gA0 = A  + (size_t)(bm + wave * 32 + lrow) * K + lcol;
    const unsigned short* gA1 = gA0 + (size_t)16 * K;
    const unsigned short* gB0 = Bt + (size_t)(bn + wave * 32 + lrow) * K + lcol;
    const unsigned short* gB1 = gB0 + (size_t)16 * K;
    unsigned short* lA0 = &As[(wave * 32) * 32];
    unsigned short* lA1 = &As[(wave * 32 + 16) * 32];
    unsigned short* lB0 = &Bs[(wave * 32) * 32];
    unsigned short* lB1 = &Bs[(wave * 32 + 16) * 32];

    for (int k0 = 0; k0 < K; k0 += 32) {
        __syncthreads();
        gll16(gA0 + k0, lA0);
        gll16(gA1 + k0, lA1);
        gll16(gB0 + k0, lB0);
        gll16(gB1 + k0, lB1);
        __syncthreads();
        bf16x8 af[4], bfr[4];
        #pragma unroll
        for (int i = 0; i < 4; ++i)
            af[i] = *(const bf16x8*)&As[(wm + i * 16 + lm) * 32 + quad * 8];
        #pragma unroll
        for (int j = 0; j < 4; ++j)
            bfr[j] = *(const bf16x8*)&Bs[(wn + j * 16 + lm) * 32 + quad * 8];
        #pragma unroll
        for (int i = 0; i < 4; ++i)
            #pragma unroll
            for (int j = 0; j < 4; ++j)
                acc[i][j] = __builtin_amdgcn_mfma_f32_16x16x32_bf16(
                    af[i], bfr[j], acc[i][j], 0, 0, 0);
    }

    #pragma unroll
    for (int i = 0; i < 4; ++i) {
        #pragma unroll
        for (int r = 0; r < 4; ++r) {
            const int row = bm + wm + i * 16 + quad * 4 + r;
            #pragma unroll
            for (int j = 0; j < 4; ++j) {
                const int col = bn + wn + j * 16 + lm;
                float v = acc[i][j][r];
                if constexpr (MODE == 0) {
                    ((unsigned short*)Cp)[(size_t)row * N + col] = f2h(v);
                } else {
                    ((float*)Cp)[(size_t)row * N + col] = v + bias[col];
                }
            }
        }
    }
}

// Sparse attention v4: block = 256 threads = 32 queries x 8 key-splits for
// one (b, h, 32-query chunk). Grid = 2048 blocks. Single-pass softmax (no max
// subtraction: |s| <~ 10 << 88). NO dynamically-indexed private arrays (v3's
// scratch-spill bug: 163 MB WRITE_SIZE): global loops fully unrolled, final
// reduction is a butterfly reduce-scatter leaving each lane its own 8 dims
// in fixed registers.
__global__ __launch_bounds__(256) void attn_kernel(
    const unsigned short* __restrict__ qkv,   // fp16 (B*T) x 3072
    unsigned short* __restrict__ attn_out)    // (B*T) x D bf16
{
    __shared__ __align__(16) unsigned short smem[72 * (2 * 128 + 2 * 47)];  // 50400 B
    unsigned short* Kg = smem;                   // [128][72] swizzled rows
    unsigned short* Vg = smem + 128 * 72;        // [128][72] swizzled rows
    unsigned short* Kl = smem + 2 * 128 * 72;    // [47][72]
    unsigned short* Vl = Kl + 47 * 72;

    const int tid   = threadIdx.x;
    const int bx    = blockIdx.x;
    const int chunk = bx & 63;
    const int bh    = bx >> 6;
    const int b     = bh >> 4;
    const int h     = bh & 15;
    const int t0    = chunk * 32;
    const int qloc  = tid >> 3;       // 0..31
    const int ks    = tid & 7;        // 0..7
    const int tq    = t0 + qloc;

    const size_t rowK = (size_t)(b * TT) * QKVLD + 1024 + h * HD;

    // ---- stage global K/V (swizzled rows) + local K/V ----
    {
        const int r = tid >> 1, hfi = tid & 1;
        const int g = ((r & 15) << 3) | (r >> 4);   // inverse row swizzle
        const unsigned short* kr = qkv + rowK + (size_t)g * 16 * QKVLD + hfi * 32;
        const unsigned short* vr = kr + 1024;
        unsigned short* kd = Kg + r * 72 + hfi * 32;
        unsigned short* vd = Vg + r * 72 + hfi * 32;
        #pragma unroll
        for (int j = 0; j < 4; ++j) {
            *(uint4*)(kd + j * 8) = *(const uint4*)(kr + j * 8);
            *(uint4*)(vd + j * 8) = *(const uint4*)(vr + j * 8);
        }
        if (r < 47) {
            const int t = t0 + r - 15;
            unsigned short* kld = Kl + r * 72 + hfi * 32;
            unsigned short* vld = Vl + r * 72 + hfi * 32;
            if (t < 0) {   // zero rows: logit 0 + no V contribution (= reference pad)
                uint4 z = { 0, 0, 0, 0 };
                #pragma unroll
                for (int j = 0; j < 4; ++j) { *(uint4*)(kld + j * 8) = z; *(uint4*)(vld + j * 8) = z; }
            } else {
                const unsigned short* klr = qkv + rowK + (size_t)t * QKVLD + hfi * 32;
                const unsigned short* vlr = klr + 1024;
                #pragma unroll
                for (int j = 0; j < 4; ++j) {
                    *(uint4*)(kld + j * 8) = *(const uint4*)(klr + j * 8);
                    *(uint4*)(vld + j * 8) = *(const uint4*)(vlr + j * 8);
                }
            }
        }
    }

    // ---- load scaled q (0.125 = pow2, exact in fp16) ----
    h2 qh[32];
    {
        const unsigned short* qrow = qkv + (size_t)(b * TT + tq) * QKVLD + h * HD;
        const h2 sc = { (_Float16)0.125f, (_Float16)0.125f };
        #pragma unroll
        for (int i = 0; i < 8; ++i) {
            union { uint4 u; h2 hh[4]; } U;
            U.u = *(const uint4*)(qrow + i * 8);
            qh[4 * i + 0] = U.hh[0] * sc; qh[4 * i + 1] = U.hh[1] * sc;
            qh[4 * i + 2] = U.hh[2] * sc; qh[4 * i + 3] = U.hh[3] * sc;
        }
    }

    __syncthreads();

    auto score = [&](const unsigned short* kp) -> float {
        float s0 = 0.f, s1 = 0.f, s2 = 0.f, s3 = 0.f;
        #pragma unroll
        for (int c = 0; c < 8; ++c) {
            union { uint4 u; h2 hh[4]; } U;
            U.u = *(const uint4*)(kp + c * 8);
            s0 = DOT2(U.hh[0], qh[4 * c + 0], s0);
            s1 = DOT2(U.hh[1], qh[4 * c + 1], s1);
            s2 = DOT2(U.hh[2], qh[4 * c + 2], s2);
            s3 = DOT2(U.hh[3], qh[4 * c + 3], s3);
        }
        return (s0 + s1) + (s2 + s3);
    };

    h2 out2[32];
    #pragma unroll
    for (int i = 0; i < 32; ++i) out2[i] = (h2){ (_Float16)0.f, (_Float16)0.f };

    // ---- local phase: my 2 window keys w = 2ks, 2ks+1 (rows qloc+w) ----
    float pl0 = __expf(score(Kl + (qloc + 2 * ks + 0) * 72));
    float pl1 = __expf(score(Kl + (qloc + 2 * ks + 1) * 72));
    float den = pl0 + pl1;
    den += __shfl_xor(den, 1, 64);
    den += __shfl_xor(den, 2, 64);
    den += __shfl_xor(den, 4, 64);
    const float inv = 1.f / den;
    #pragma unroll
    for (int w = 0; w < 2; ++w) {
        const float pn = (w ? pl1 : pl0) * inv;
        h2 ph; ph.x = (_Float16)pn; ph.y = ph.x;
        const unsigned short* vp = Vl + (qloc + 2 * ks + w) * 72;
        #pragma unroll
        for (int c = 0; c < 8; ++c) {
            union { uint4 u; h2 hh[4]; } U;
            U.u = *(const uint4*)(vp + c * 8);
            out2[4 * c + 0] += ph * U.hh[0]; out2[4 * c + 1] += ph * U.hh[1];
            out2[4 * c + 2] += ph * U.hh[2]; out2[4 * c + 3] += ph * U.hh[3];
        }
    }

    // ---- global phase: my 16 keys g = ks*16 + i (FULLY unrolled: constant idx) ----
    float pg[16];
    float deng = 0.f;
    #pragma unroll
    for (int i = 0; i < 16; ++i) {
        const int g = ks * 16 + i;
        const int row = ((g & 7) << 4) | (g >> 3);
        const float e = __expf(score(Kg + row * 72));
        pg[i] = e; deng += e;
    }
    deng += __shfl_xor(deng, 1, 64);
    deng += __shfl_xor(deng, 2, 64);
    deng += __shfl_xor(deng, 4, 64);
    const float invg = 1.f / deng;
    #pragma unroll
    for (int i = 0; i < 16; ++i) {
        const int g = ks * 16 + i;
        const int row = ((g & 7) << 4) | (g >> 3);
        const float pn = pg[i] * invg;
        h2 ph; ph.x = (_Float16)pn; ph.y = ph.x;
        const unsigned short* vp = Vg + row * 72;
        #pragma unroll
        for (int c = 0; c < 8; ++c) {
            union { uint4 u; h2 hh[4]; } U;
            U.u = *(const uint4*)(vp + c * 8);
            out2[4 * c + 0] += ph * U.hh[0]; out2[4 * c + 1] += ph * U.hh[1];
            out2[4 * c + 2] += ph * U.hh[2]; out2[4 * c + 3] += ph * U.hh[3];
        }
    }

    // ---- butterfly reduce-scatter over the 8 ks lanes ----
    // stage 1 (xor 4): keep 16 h2 (32 dims selected by ks bit2)
    h2 a[16];
    {
        const bool hi = (ks & 4) != 0;
        #pragma unroll
        for (int i = 0; i < 16; ++i) {
            h2 snd  = hi ? out2[i] : out2[i + 16];
            h2 rcv  = shfl_h2(snd, 4);
            a[i] = (hi ? out2[i + 16] : out2[i]) + rcv;
        }
    }
    // stage 2 (xor 2): keep 8 h2
    h2 bb[8];
    {
        const bool hi = (ks & 2) != 0;
        #pragma unroll
        for (int i = 0; i < 8; ++i) {
            h2 snd  = hi ? a[i] : a[i + 8];
            h2 rcv  = shfl_h2(snd, 2);
            bb[i] = (hi ? a[i + 8] : a[i]) + rcv;
        }
    }
    // stage 3 (xor 1): keep 4 h2 = this lane's dims [8ks, 8ks+8)
    h2 c4[4];
    {
        const bool hi = (ks & 1) != 0;
        #pragma unroll
        for (int i = 0; i < 4; ++i) {
            h2 snd  = hi ? bb[i] : bb[i + 4];
            h2 rcv  = shfl_h2(snd, 1);
            c4[i] = (hi ? bb[i + 4] : bb[i]) + rcv;
        }
    }

    // ---- write my 8 dims as bf16 (fixed registers, no dynamic index) ----
    {
        unsigned int pk[4];
        #pragma unroll
        for (int j = 0; j < 4; ++j)
            pk[j] = (unsigned int)f2bf((float)c4[j].x) | ((unsigned int)f2bf((float)c4[j].y) << 16);
        uint4 st = { pk[0], pk[1], pk[2], pk[3] };
        *(uint4*)(attn_out + (size_t)(b * TT + tq) * DD + h * HD + ks * 8) = st;
    }
}

extern "C" void kernel_launch(void* const* d_in, const int* in_sizes, int n_in,
                              void* d_out, int out_size, void* d_ws, size_t ws_size,
                              hipStream_t stream) {
    const float* x      = (const float*)d_in[0];  // (B*T) x D fp32
    const float* w_qkv  = (const float*)d_in[1];  // D x 3D fp32
    const float* w_proj = (const float*)d_in[2];  // D x D fp32
    const float* b_proj = (const float*)d_in[3];  // D fp32

    // ws layout (41.94 MB total):
    //   qkv fp16 (4096x3072)      : 25.166 MB
    //   xb/attnb bf16 (4096x1024) :  8.389 MB  (aliased: xb dead after gemm1)
    //   wqkvT bf16 (3072x1024)    :  6.291 MB
    //   wprojT bf16 (1024x1024)   :  2.097 MB
    char* ws = (char*)d_ws;
    unsigned short* qkv    = (unsigned short*)ws;
    unsigned short* xb     = (unsigned short*)(ws + 25165824);
    unsigned short* attnb  = xb;
    unsigned short* wqkvT  = (unsigned short*)(ws + 25165824 + 8388608);
    unsigned short* wprojT = (unsigned short*)(ws + 25165824 + 8388608 + 6291456);
    float* out = (float*)d_out;

    // 0) pre-convert: x -> bf16; weights -> transposed bf16
    conv_bf16_kernel<<<(4096 * 1024) / (256 * 8), 256, 0, stream>>>(x, xb);
    transpose_bf16_kernel<<<dim3(3072 / 32, 1024 / 32), 256, 0, stream>>>(
        w_qkv, wqkvT, 1024, 3072);
    transpose_bf16_kernel<<<dim3(1024 / 32, 1024 / 32), 256, 0, stream>>>(
        w_proj, wprojT, 1024, 1024);

    // 1) qkv = x @ w_qkv  (bf16 MFMA, fp16 out)
    gemm_kernel<0><<<dim3(3072 / 128, 4096 / 128), 256, 0, stream>>>(
        xb, wqkvT, qkv, nullptr, 4096, 3072, 1024);

    // 2) sparse attention (local window + global strided), bf16 out
    attn_kernel<<<dim3(BB * HH * (TT / 32)), 256, 0, stream>>>(qkv, attnb);

    // 3) out = attnb @ w_proj + b_proj, fp32 out
    gemm_kernel<1><<<dim3(1024 / 128, 4096 / 128), 256, 0, stream>>>(
        attnb, wprojT, out, b_proj, 4096, 1024, 1024);
}

// Round 10
// 181.531 us; speedup vs baseline: 4.5943x; 1.0293x over previous
//
#include <hip/hip_runtime.h>
#include <hip/hip_bf16.h>

// Problem constants (fixed by setup_inputs)
#define BB 2
#define TT 2048
#define DD 1024
#define HH 16
#define HD 64
#define WIN 16
#define NG 128          // T / stride global tokens
#define QKVLD 3072      // 3*D row stride of qkv

typedef __bf16 bf16x8 __attribute__((ext_vector_type(8)));
typedef float f32x4 __attribute__((ext_vector_type(4)));
typedef _Float16 h2 __attribute__((ext_vector_type(2)));

__device__ __forceinline__ unsigned short f2bf(float f) {
    union { float f; unsigned int i; } x; x.f = f;
    unsigned int r = x.i + 0x7FFFu + ((x.i >> 16) & 1u);
    return (unsigned short)(r >> 16);
}
__device__ __forceinline__ unsigned short f2h(float f) {
    union { _Float16 h; unsigned short u; } x; x.h = (_Float16)f; return x.u;
}
__device__ __forceinline__ h2 shfl_h2(h2 v, int mask) {
    union { h2 h; int i; } X; X.h = v;
    X.i = __shfl_xor(X.i, mask, 64);
    return X.h;
}

#if defined(__has_builtin)
#  if __has_builtin(__builtin_amdgcn_fdot2)
#    define DOT2(a, b, c) __builtin_amdgcn_fdot2((a), (b), (c), false)
#  endif
#endif
#ifndef DOT2
#  define DOT2(a, b, c) ((c) + (float)(a).x * (float)(b).x + (float)(a).y * (float)(b).y)
#endif

// async global->LDS, 16 B per lane; LDS dest = wave-uniform base + lane*16
__device__ __forceinline__ void gll16(const unsigned short* g, unsigned short* l) {
    __builtin_amdgcn_global_load_lds(
        (const __attribute__((address_space(1))) void*)g,
        (__attribute__((address_space(3))) void*)l,
        16, 0, 0);
}

// ---------------- fused pre-pass (one dispatch, role per block) ----------
//   blocks [0, 2048)         : x fp32 -> xb bf16 (8 elems/thread)
//   blocks [2048, 5120)      : w_qkv (1024x3072) -> wqkvT (3072x1024) bf16
//   blocks [5120, 6144)      : w_proj (1024x1024) -> wprojT (1024x1024) bf16
__global__ __launch_bounds__(256) void prepass_kernel(
    const float* __restrict__ x,
    const float* __restrict__ w_qkv,
    const float* __restrict__ w_proj,
    unsigned short* __restrict__ xb,
    unsigned short* __restrict__ wqkvT,
    unsigned short* __restrict__ wprojT)
{
    __shared__ float tile[32][33];
    const int bid = blockIdx.x;
    const int tid = threadIdx.x;

    if (bid < 2048) {
        const size_t i = ((size_t)bid * 256 + tid) * 8;
        float4 f0 = *(const float4*)(x + i);
        float4 f1 = *(const float4*)(x + i + 4);
        ushort4 a = { f2bf(f0.x), f2bf(f0.y), f2bf(f0.z), f2bf(f0.w) };
        ushort4 b = { f2bf(f1.x), f2bf(f1.y), f2bf(f1.z), f2bf(f1.w) };
        *(ushort4*)(xb + i) = a;
        *(ushort4*)(xb + i + 4) = b;
        return;
    }

    const float* w;
    unsigned short* wT;
    int nblk, kblk, N;
    if (bid < 5120) {
        const int b2 = bid - 2048;
        w = w_qkv; wT = wqkvT; N = 3072;
        nblk = b2 % 96; kblk = b2 / 96;
    } else {
        const int b2 = bid - 5120;
        w = w_proj; wT = wprojT; N = 1024;
        nblk = b2 % 32; kblk = b2 / 32;
    }
    const int K = 1024;
    const int n0 = nblk * 32, k0 = kblk * 32;
    const int tx = tid & 31, ty = tid >> 5;
    #pragma unroll
    for (int i = 0; i < 4; ++i)
        tile[ty + 8 * i][tx] = w[(size_t)(k0 + ty + 8 * i) * N + n0 + tx];
    __syncthreads();
    #pragma unroll
    for (int i = 0; i < 4; ++i)
        wT[(size_t)(n0 + ty + 8 * i) * K + k0 + tx] = f2bf(tile[tx][ty + 8 * i]);
}

// ---------------- m97-style GEMM: C = A(MxK) @ Bt(NxK)^T ------------------
// A, Bt bf16 row-major. 128x128 tile, BK=32, global_load_lds(16B) staging,
// 4 waves each computing 64x64 via 4x4 16x16x32 MFMA fragments.
// MODE 0: fp16 out, no bias. MODE 1: fp32 out + fp32 bias.
template<int MODE>
__global__ __launch_bounds__(256) void gemm_kernel(
    const unsigned short* __restrict__ A,
    const unsigned short* __restrict__ Bt,
    void* __restrict__ Cp,
    const float* __restrict__ bias,
    int M, int N, int K)
{
    __shared__ __align__(16) unsigned short As[128 * 32];
    __shared__ __align__(16) unsigned short Bs[128 * 32];
    const int tid  = threadIdx.x;
    const int wave = tid >> 6;
    const int lane = tid & 63;
    const int lm   = lane & 15;
    const int quad = lane >> 4;
    const int wm   = (wave >> 1) * 64;   // wave tile row offset
    const int wn   = (wave & 1) * 64;    // wave tile col offset
    const int bm   = blockIdx.y * 128;
    const int bn   = blockIdx.x * 128;

    f32x4 acc[4][4];
    const f32x4 z4 = { 0.f, 0.f, 0.f, 0.f };
    #pragma unroll
    for (int i = 0; i < 4; ++i)
        #pragma unroll
        for (int j = 0; j < 4; ++j) acc[i][j] = z4;

    const int lrow = lane >> 2, lcol = (lane & 3) * 8;
    const unsigned short* gA0 = A  + (size_t)(bm + wave * 32 + lrow) * K + lcol;
    const unsigned short* gA1 = gA0 + (size_t)16 * K;
    const unsigned short* gB0 = Bt + (size_t)(bn + wave * 32 + lrow) * K + lcol;
    const unsigned short* gB1 = gB0 + (size_t)16 * K;
    unsigned short* lA0 = &As[(wave * 32) * 32];
    unsigned short* lA1 = &As[(wave * 32 + 16) * 32];
    unsigned short* lB0 = &Bs[(wave * 32) * 32];
    unsigned short* lB1 = &Bs[(wave * 32 + 16) * 32];

    for (int k0 = 0; k0 < K; k0 += 32) {
        __syncthreads();
        gll16(gA0 + k0, lA0);
        gll16(gA1 + k0, lA1);
        gll16(gB0 + k0, lB0);
        gll16(gB1 + k0, lB1);
        __syncthreads();
        bf16x8 af[4], bfr[4];
        #pragma unroll
        for (int i = 0; i < 4; ++i)
            af[i] = *(const bf16x8*)&As[(wm + i * 16 + lm) * 32 + quad * 8];
        #pragma unroll
        for (int j = 0; j < 4; ++j)
            bfr[j] = *(const bf16x8*)&Bs[(wn + j * 16 + lm) * 32 + quad * 8];
        #pragma unroll
        for (int i = 0; i < 4; ++i)
            #pragma unroll
            for (int j = 0; j < 4; ++j)
                acc[i][j] = __builtin_amdgcn_mfma_f32_16x16x32_bf16(
                    af[i], bfr[j], acc[i][j], 0, 0, 0);
    }

    #pragma unroll
    for (int i = 0; i < 4; ++i) {
        #pragma unroll
        for (int r = 0; r < 4; ++r) {
            const int row = bm + wm + i * 16 + quad * 4 + r;
            #pragma unroll
            for (int j = 0; j < 4; ++j) {
                const int col = bn + wn + j * 16 + lm;
                float v = acc[i][j][r];
                if constexpr (MODE == 0) {
                    ((unsigned short*)Cp)[(size_t)row * N + col] = f2h(v);
                } else {
                    ((float*)Cp)[(size_t)row * N + col] = v + bias[col];
                }
            }
        }
    }
}

// Sparse attention v4: block = 256 threads = 32 queries x 8 key-splits for
// one (b, h, 32-query chunk). Grid = 2048 blocks. Single-pass softmax (no max
// subtraction: |s| <~ 10 << 88). No dynamically-indexed private arrays
// (scratch-spill hazard): loops fully unrolled; final reduction is a
// butterfly reduce-scatter leaving each lane its own 8 dims in fixed regs.
__global__ __launch_bounds__(256) void attn_kernel(
    const unsigned short* __restrict__ qkv,   // fp16 (B*T) x 3072
    unsigned short* __restrict__ attn_out)    // (B*T) x D bf16
{
    __shared__ __align__(16) unsigned short smem[72 * (2 * 128 + 2 * 47)];  // 50400 B
    unsigned short* Kg = smem;                   // [128][72] swizzled rows
    unsigned short* Vg = smem + 128 * 72;        // [128][72] swizzled rows
    unsigned short* Kl = smem + 2 * 128 * 72;    // [47][72]
    unsigned short* Vl = Kl + 47 * 72;

    const int tid   = threadIdx.x;
    const int bx    = blockIdx.x;
    const int chunk = bx & 63;
    const int bh    = bx >> 6;
    const int b     = bh >> 4;
    const int h     = bh & 15;
    const int t0    = chunk * 32;
    const int qloc  = tid >> 3;       // 0..31
    const int ks    = tid & 7;        // 0..7
    const int tq    = t0 + qloc;

    const size_t rowK = (size_t)(b * TT) * QKVLD + 1024 + h * HD;

    // ---- stage global K/V (swizzled rows) + local K/V ----
    {
        const int r = tid >> 1, hfi = tid & 1;
        const int g = ((r & 15) << 3) | (r >> 4);   // inverse row swizzle
        const unsigned short* kr = qkv + rowK + (size_t)g * 16 * QKVLD + hfi * 32;
        const unsigned short* vr = kr + 1024;
        unsigned short* kd = Kg + r * 72 + hfi * 32;
        unsigned short* vd = Vg + r * 72 + hfi * 32;
        #pragma unroll
        for (int j = 0; j < 4; ++j) {
            *(uint4*)(kd + j * 8) = *(const uint4*)(kr + j * 8);
            *(uint4*)(vd + j * 8) = *(const uint4*)(vr + j * 8);
        }
        if (r < 47) {
            const int t = t0 + r - 15;
            unsigned short* kld = Kl + r * 72 + hfi * 32;
            unsigned short* vld = Vl + r * 72 + hfi * 32;
            if (t < 0) {   // zero rows: logit 0 + no V contribution (= reference pad)
                uint4 z = { 0, 0, 0, 0 };
                #pragma unroll
                for (int j = 0; j < 4; ++j) { *(uint4*)(kld + j * 8) = z; *(uint4*)(vld + j * 8) = z; }
            } else {
                const unsigned short* klr = qkv + rowK + (size_t)t * QKVLD + hfi * 32;
                const unsigned short* vlr = klr + 1024;
                #pragma unroll
                for (int j = 0; j < 4; ++j) {
                    *(uint4*)(kld + j * 8) = *(const uint4*)(klr + j * 8);
                    *(uint4*)(vld + j * 8) = *(const uint4*)(vlr + j * 8);
                }
            }
        }
    }

    // ---- load scaled q (0.125 = pow2, exact in fp16) ----
    h2 qh[32];
    {
        const unsigned short* qrow = qkv + (size_t)(b * TT + tq) * QKVLD + h * HD;
        const h2 sc = { (_Float16)0.125f, (_Float16)0.125f };
        #pragma unroll
        for (int i = 0; i < 8; ++i) {
            union { uint4 u; h2 hh[4]; } U;
            U.u = *(const uint4*)(qrow + i * 8);
            qh[4 * i + 0] = U.hh[0] * sc; qh[4 * i + 1] = U.hh[1] * sc;
            qh[4 * i + 2] = U.hh[2] * sc; qh[4 * i + 3] = U.hh[3] * sc;
        }
    }

    __syncthreads();

    auto score = [&](const unsigned short* kp) -> float {
        float s0 = 0.f, s1 = 0.f, s2 = 0.f, s3 = 0.f;
        #pragma unroll
        for (int c = 0; c < 8; ++c) {
            union { uint4 u; h2 hh[4]; } U;
            U.u = *(const uint4*)(kp + c * 8);
            s0 = DOT2(U.hh[0], qh[4 * c + 0], s0);
            s1 = DOT2(U.hh[1], qh[4 * c + 1], s1);
            s2 = DOT2(U.hh[2], qh[4 * c + 2], s2);
            s3 = DOT2(U.hh[3], qh[4 * c + 3], s3);
        }
        return (s0 + s1) + (s2 + s3);
    };

    h2 out2[32];
    #pragma unroll
    for (int i = 0; i < 32; ++i) out2[i] = (h2){ (_Float16)0.f, (_Float16)0.f };

    // ---- local phase: my 2 window keys w = 2ks, 2ks+1 (rows qloc+w) ----
    float pl0 = __expf(score(Kl + (qloc + 2 * ks + 0) * 72));
    float pl1 = __expf(score(Kl + (qloc + 2 * ks + 1) * 72));
    float den = pl0 + pl1;
    den += __shfl_xor(den, 1, 64);
    den += __shfl_xor(den, 2, 64);
    den += __shfl_xor(den, 4, 64);
    const float inv = 1.f / den;
    #pragma unroll
    for (int w = 0; w < 2; ++w) {
        const float pn = (w ? pl1 : pl0) * inv;
        h2 ph; ph.x = (_Float16)pn; ph.y = ph.x;
        const unsigned short* vp = Vl + (qloc + 2 * ks + w) * 72;
        #pragma unroll
        for (int c = 0; c < 8; ++c) {
            union { uint4 u; h2 hh[4]; } U;
            U.u = *(const uint4*)(vp + c * 8);
            out2[4 * c + 0] += ph * U.hh[0]; out2[4 * c + 1] += ph * U.hh[1];
            out2[4 * c + 2] += ph * U.hh[2]; out2[4 * c + 3] += ph * U.hh[3];
        }
    }

    // ---- global phase: my 16 keys g = ks*16 + i (fully unrolled) ----
    float pg[16];
    float deng = 0.f;
    #pragma unroll
    for (int i = 0; i < 16; ++i) {
        const int g = ks * 16 + i;
        const int row = ((g & 7) << 4) | (g >> 3);
        const float e = __expf(score(Kg + row * 72));
        pg[i] = e; deng += e;
    }
    deng += __shfl_xor(deng, 1, 64);
    deng += __shfl_xor(deng, 2, 64);
    deng += __shfl_xor(deng, 4, 64);
    const float invg = 1.f / deng;
    #pragma unroll
    for (int i = 0; i < 16; ++i) {
        const int g = ks * 16 + i;
        const int row = ((g & 7) << 4) | (g >> 3);
        const float pn = pg[i] * invg;
        h2 ph; ph.x = (_Float16)pn; ph.y = ph.x;
        const unsigned short* vp = Vg + row * 72;
        #pragma unroll
        for (int c = 0; c < 8; ++c) {
            union { uint4 u; h2 hh[4]; } U;
            U.u = *(const uint4*)(vp + c * 8);
            out2[4 * c + 0] += ph * U.hh[0]; out2[4 * c + 1] += ph * U.hh[1];
            out2[4 * c + 2] += ph * U.hh[2]; out2[4 * c + 3] += ph * U.hh[3];
        }
    }

    // ---- butterfly reduce-scatter over the 8 ks lanes ----
    h2 a[16];
    {
        const bool hi = (ks & 4) != 0;
        #pragma unroll
        for (int i = 0; i < 16; ++i) {
            h2 snd  = hi ? out2[i] : out2[i + 16];
            h2 rcv  = shfl_h2(snd, 4);
            a[i] = (hi ? out2[i + 16] : out2[i]) + rcv;
        }
    }
    h2 bb[8];
    {
        const bool hi = (ks & 2) != 0;
        #pragma unroll
        for (int i = 0; i < 8; ++i) {
            h2 snd  = hi ? a[i] : a[i + 8];
            h2 rcv  = shfl_h2(snd, 2);
            bb[i] = (hi ? a[i + 8] : a[i]) + rcv;
        }
    }
    h2 c4[4];
    {
        const bool hi = (ks & 1) != 0;
        #pragma unroll
        for (int i = 0; i < 4; ++i) {
            h2 snd  = hi ? bb[i] : bb[i + 4];
            h2 rcv  = shfl_h2(snd, 1);
            c4[i] = (hi ? bb[i + 4] : bb[i]) + rcv;
        }
    }

    // ---- write my 8 dims as bf16 (fixed registers, no dynamic index) ----
    {
        unsigned int pk[4];
        #pragma unroll
        for (int j = 0; j < 4; ++j)
            pk[j] = (unsigned int)f2bf((float)c4[j].x) | ((unsigned int)f2bf((float)c4[j].y) << 16);
        uint4 st = { pk[0], pk[1], pk[2], pk[3] };
        *(uint4*)(attn_out + (size_t)(b * TT + tq) * DD + h * HD + ks * 8) = st;
    }
}

extern "C" void kernel_launch(void* const* d_in, const int* in_sizes, int n_in,
                              void* d_out, int out_size, void* d_ws, size_t ws_size,
                              hipStream_t stream) {
    const float* x      = (const float*)d_in[0];  // (B*T) x D fp32
    const float* w_qkv  = (const float*)d_in[1];  // D x 3D fp32
    const float* w_proj = (const float*)d_in[2];  // D x D fp32
    const float* b_proj = (const float*)d_in[3];  // D fp32

    // ws layout (41.94 MB total):
    //   qkv fp16 (4096x3072)      : 25.166 MB
    //   xb/attnb bf16 (4096x1024) :  8.389 MB  (aliased: xb dead after gemm1)
    //   wqkvT bf16 (3072x1024)    :  6.291 MB
    //   wprojT bf16 (1024x1024)   :  2.097 MB
    char* ws = (char*)d_ws;
    unsigned short* qkv    = (unsigned short*)ws;
    unsigned short* xb     = (unsigned short*)(ws + 25165824);
    unsigned short* attnb  = xb;
    unsigned short* wqkvT  = (unsigned short*)(ws + 25165824 + 8388608);
    unsigned short* wprojT = (unsigned short*)(ws + 25165824 + 8388608 + 6291456);
    float* out = (float*)d_out;

    // 0) fused pre-pass: x -> bf16; both weights -> transposed bf16
    prepass_kernel<<<6144, 256, 0, stream>>>(x, w_qkv, w_proj, xb, wqkvT, wprojT);

    // 1) qkv = x @ w_qkv  (bf16 MFMA, fp16 out)
    gemm_kernel<0><<<dim3(3072 / 128, 4096 / 128), 256, 0, stream>>>(
        xb, wqkvT, qkv, nullptr, 4096, 3072, 1024);

    // 2) sparse attention (local window + global strided), bf16 out
    attn_kernel<<<dim3(BB * HH * (TT / 32)), 256, 0, stream>>>(qkv, attnb);

    // 3) out = attnb @ w_proj + b_proj, fp32 out
    gemm_kernel<1><<<dim3(1024 / 128, 4096 / 128), 256, 0, stream>>>(
        attnb, wprojT, out, b_proj, 4096, 1024, 1024);
}

// Round 11
// 177.182 us; speedup vs baseline: 4.7070x; 1.0246x over previous
//
#include <hip/hip_runtime.h>
#include <hip/hip_bf16.h>

// Problem constants (fixed by setup_inputs)
#define BB 2
#define TT 2048
#define DD 1024
#define HH 16
#define HD 64
#define WIN 16
#define NG 128          // T / stride global tokens
#define QKVLD 3072      // 3*D row stride of qkv

typedef __bf16 bf16x8 __attribute__((ext_vector_type(8)));
typedef float f32x4 __attribute__((ext_vector_type(4)));
typedef _Float16 h2 __attribute__((ext_vector_type(2)));

__device__ __forceinline__ unsigned short f2bf(float f) {
    union { float f; unsigned int i; } x; x.f = f;
    unsigned int r = x.i + 0x7FFFu + ((x.i >> 16) & 1u);
    return (unsigned short)(r >> 16);
}
__device__ __forceinline__ unsigned short f2h(float f) {
    union { _Float16 h; unsigned short u; } x; x.h = (_Float16)f; return x.u;
}
__device__ __forceinline__ h2 shfl_h2(h2 v, int mask) {
    union { h2 h; int i; } X; X.h = v;
    X.i = __shfl_xor(X.i, mask, 64);
    return X.h;
}

#if defined(__has_builtin)
#  if __has_builtin(__builtin_amdgcn_fdot2)
#    define DOT2(a, b, c) __builtin_amdgcn_fdot2((a), (b), (c), false)
#  endif
#endif
#ifndef DOT2
#  define DOT2(a, b, c) ((c) + (float)(a).x * (float)(b).x + (float)(a).y * (float)(b).y)
#endif

// async global->LDS, 16 B per lane; LDS dest = wave-uniform base + lane*16
__device__ __forceinline__ void gll16(const unsigned short* g, unsigned short* l) {
    __builtin_amdgcn_global_load_lds(
        (const __attribute__((address_space(1))) void*)g,
        (__attribute__((address_space(3))) void*)l,
        16, 0, 0);
}

// ---------------- fused pre-pass (one dispatch, role per block) ----------
//   blocks [0, 2048)     : x fp32 -> xb bf16 (8 elems/thread)
//   blocks [2048, 2816)  : w_qkv (1024x3072) -> wqkvT (3072x1024) bf16, 64x64 tiles
//   blocks [2816, 3072)  : w_proj (1024x1024) -> wprojT (1024x1024) bf16, 64x64 tiles
__global__ __launch_bounds__(256) void prepass_kernel(
    const float* __restrict__ x,
    const float* __restrict__ w_qkv,
    const float* __restrict__ w_proj,
    unsigned short* __restrict__ xb,
    unsigned short* __restrict__ wqkvT,
    unsigned short* __restrict__ wprojT)
{
    __shared__ float tile[64][65];
    const int bid = blockIdx.x;
    const int tid = threadIdx.x;

    if (bid < 2048) {
        const size_t i = ((size_t)bid * 256 + tid) * 8;
        float4 f0 = *(const float4*)(x + i);
        float4 f1 = *(const float4*)(x + i + 4);
        ushort4 a = { f2bf(f0.x), f2bf(f0.y), f2bf(f0.z), f2bf(f0.w) };
        ushort4 b = { f2bf(f1.x), f2bf(f1.y), f2bf(f1.z), f2bf(f1.w) };
        *(ushort4*)(xb + i) = a;
        *(ushort4*)(xb + i + 4) = b;
        return;
    }

    const float* w;
    unsigned short* wT;
    int nblk, kblk, N;
    if (bid < 2816) {
        const int b2 = bid - 2048;
        w = w_qkv; wT = wqkvT; N = 3072;
        nblk = b2 % 48; kblk = b2 / 48;
    } else {
        const int b2 = bid - 2816;
        w = w_proj; wT = wprojT; N = 1024;
        nblk = b2 % 16; kblk = b2 / 16;
    }
    const int K = 1024;
    const int n0 = nblk * 64, k0 = kblk * 64;

    // read: 64(k) x 64(n) fp32, coalesced 16 floats per thread
    {
        const int krow = tid >> 2;             // 0..63
        const int nc0  = (tid & 3) * 16;       // 0,16,32,48
        const float* src = w + (size_t)(k0 + krow) * N + n0 + nc0;
        float4 f0 = *(const float4*)(src);
        float4 f1 = *(const float4*)(src + 4);
        float4 f2 = *(const float4*)(src + 8);
        float4 f3 = *(const float4*)(src + 12);
        *(float4*)&tile[krow][nc0]      = f0;
        *(float4*)&tile[krow][nc0 + 4]  = f1;
        *(float4*)&tile[krow][nc0 + 8]  = f2;
        *(float4*)&tile[krow][nc0 + 12] = f3;
    }
    __syncthreads();
    // write: each thread stores 2 x 16B (8 bf16 along k); per wave: 8 rows x 128 B
    #pragma unroll
    for (int rep = 0; rep < 2; ++rep) {
        const int n   = (tid >> 3) + rep * 32;  // 0..63
        const int kc0 = (tid & 7) * 8;          // 0..56
        union { uint4 v; unsigned short u[8]; } o;
        #pragma unroll
        for (int j = 0; j < 8; ++j) o.u[j] = f2bf(tile[kc0 + j][n]);
        *(uint4*)(wT + (size_t)(n0 + n) * K + k0 + kc0) = o.v;
    }
}

// ---------------- m97-style GEMM: C = A(MxK) @ Bt(NxK)^T ------------------
// A, Bt bf16 row-major. 128xTN tile, BK=32, global_load_lds(16B) staging,
// 4 waves each computing 64x(TN/2) via 4x(TN/32) 16x16x32 MFMA fragments.
// MODE 0: fp16 out, no bias. MODE 1: fp32 out + fp32 bias.
template<int MODE, int TN>
__global__ __launch_bounds__(256) void gemm_kernel(
    const unsigned short* __restrict__ A,
    const unsigned short* __restrict__ Bt,
    void* __restrict__ Cp,
    const float* __restrict__ bias,
    int M, int N, int K)
{
    constexpr int NJ = TN / 32;          // frag cols per wave (4 or 2)
    constexpr int BR = TN / 4;           // B rows staged per wave (32 or 16)
    __shared__ __align__(16) unsigned short As[128 * 32];
    __shared__ __align__(16) unsigned short Bs[TN * 32];
    const int tid  = threadIdx.x;
    const int wave = tid >> 6;
    const int lane = tid & 63;
    const int lm   = lane & 15;
    const int quad = lane >> 4;
    const int wm   = (wave >> 1) * 64;       // wave tile row offset
    const int wn   = (wave & 1) * (TN / 2);  // wave tile col offset
    const int bm   = blockIdx.y * 128;
    const int bn   = blockIdx.x * TN;

    f32x4 acc[4][NJ];
    const f32x4 z4 = { 0.f, 0.f, 0.f, 0.f };
    #pragma unroll
    for (int i = 0; i < 4; ++i)
        #pragma unroll
        for (int j = 0; j < NJ; ++j) acc[i][j] = z4;

    const int lrow = lane >> 2, lcol = (lane & 3) * 8;
    const unsigned short* gA0 = A  + (size_t)(bm + wave * 32 + lrow) * K + lcol;
    const unsigned short* gA1 = gA0 + (size_t)16 * K;
    const unsigned short* gB0 = Bt + (size_t)(bn + wave * BR + lrow) * K + lcol;
    const unsigned short* gB1 = gB0 + (size_t)16 * K;
    unsigned short* lA0 = &As[(wave * 32) * 32];
    unsigned short* lA1 = &As[(wave * 32 + 16) * 32];
    unsigned short* lB0 = &Bs[(wave * BR) * 32];
    unsigned short* lB1 = &Bs[(wave * BR + 16) * 32];

    for (int k0 = 0; k0 < K; k0 += 32) {
        __syncthreads();
        gll16(gA0 + k0, lA0);
        gll16(gA1 + k0, lA1);
        gll16(gB0 + k0, lB0);
        if constexpr (BR == 32) gll16(gB1 + k0, lB1);
        __syncthreads();
        bf16x8 af[4], bfr[NJ];
        #pragma unroll
        for (int i = 0; i < 4; ++i)
            af[i] = *(const bf16x8*)&As[(wm + i * 16 + lm) * 32 + quad * 8];
        #pragma unroll
        for (int j = 0; j < NJ; ++j)
            bfr[j] = *(const bf16x8*)&Bs[(wn + j * 16 + lm) * 32 + quad * 8];
        #pragma unroll
        for (int i = 0; i < 4; ++i)
            #pragma unroll
            for (int j = 0; j < NJ; ++j)
                acc[i][j] = __builtin_amdgcn_mfma_f32_16x16x32_bf16(
                    af[i], bfr[j], acc[i][j], 0, 0, 0);
    }

    #pragma unroll
    for (int i = 0; i < 4; ++i) {
        #pragma unroll
        for (int r = 0; r < 4; ++r) {
            const int row = bm + wm + i * 16 + quad * 4 + r;
            #pragma unroll
            for (int j = 0; j < NJ; ++j) {
                const int col = bn + wn + j * 16 + lm;
                float v = acc[i][j][r];
                if constexpr (MODE == 0) {
                    ((unsigned short*)Cp)[(size_t)row * N + col] = f2h(v);
                } else {
                    ((float*)Cp)[(size_t)row * N + col] = v + bias[col];
                }
            }
        }
    }
}

// Sparse attention v4: block = 256 threads = 32 queries x 8 key-splits for
// one (b, h, 32-query chunk). Grid = 2048 blocks. Single-pass softmax (no max
// subtraction: |s| <~ 10 << 88). No dynamically-indexed private arrays
// (scratch-spill hazard): loops fully unrolled; final reduction is a
// butterfly reduce-scatter leaving each lane its own 8 dims in fixed regs.
__global__ __launch_bounds__(256) void attn_kernel(
    const unsigned short* __restrict__ qkv,   // fp16 (B*T) x 3072
    unsigned short* __restrict__ attn_out)    // (B*T) x D bf16
{
    __shared__ __align__(16) unsigned short smem[72 * (2 * 128 + 2 * 47)];  // 50400 B
    unsigned short* Kg = smem;                   // [128][72] swizzled rows
    unsigned short* Vg = smem + 128 * 72;        // [128][72] swizzled rows
    unsigned short* Kl = smem + 2 * 128 * 72;    // [47][72]
    unsigned short* Vl = Kl + 47 * 72;

    const int tid   = threadIdx.x;
    const int bx    = blockIdx.x;
    const int chunk = bx & 63;
    const int bh    = bx >> 6;
    const int b     = bh >> 4;
    const int h     = bh & 15;
    const int t0    = chunk * 32;
    const int qloc  = tid >> 3;       // 0..31
    const int ks    = tid & 7;        // 0..7
    const int tq    = t0 + qloc;

    const size_t rowK = (size_t)(b * TT) * QKVLD + 1024 + h * HD;

    // ---- stage global K/V (swizzled rows) + local K/V ----
    {
        const int r = tid >> 1, hfi = tid & 1;
        const int g = ((r & 15) << 3) | (r >> 4);   // inverse row swizzle
        const unsigned short* kr = qkv + rowK + (size_t)g * 16 * QKVLD + hfi * 32;
        const unsigned short* vr = kr + 1024;
        unsigned short* kd = Kg + r * 72 + hfi * 32;
        unsigned short* vd = Vg + r * 72 + hfi * 32;
        #pragma unroll
        for (int j = 0; j < 4; ++j) {
            *(uint4*)(kd + j * 8) = *(const uint4*)(kr + j * 8);
            *(uint4*)(vd + j * 8) = *(const uint4*)(vr + j * 8);
        }
        if (r < 47) {
            const int t = t0 + r - 15;
            unsigned short* kld = Kl + r * 72 + hfi * 32;
            unsigned short* vld = Vl + r * 72 + hfi * 32;
            if (t < 0) {   // zero rows: logit 0 + no V contribution (= reference pad)
                uint4 z = { 0, 0, 0, 0 };
                #pragma unroll
                for (int j = 0; j < 4; ++j) { *(uint4*)(kld + j * 8) = z; *(uint4*)(vld + j * 8) = z; }
            } else {
                const unsigned short* klr = qkv + rowK + (size_t)t * QKVLD + hfi * 32;
                const unsigned short* vlr = klr + 1024;
                #pragma unroll
                for (int j = 0; j < 4; ++j) {
                    *(uint4*)(kld + j * 8) = *(const uint4*)(klr + j * 8);
                    *(uint4*)(vld + j * 8) = *(const uint4*)(vlr + j * 8);
                }
            }
        }
    }

    // ---- load scaled q (0.125 = pow2, exact in fp16) ----
    h2 qh[32];
    {
        const unsigned short* qrow = qkv + (size_t)(b * TT + tq) * QKVLD + h * HD;
        const h2 sc = { (_Float16)0.125f, (_Float16)0.125f };
        #pragma unroll
        for (int i = 0; i < 8; ++i) {
            union { uint4 u; h2 hh[4]; } U;
            U.u = *(const uint4*)(qrow + i * 8);
            qh[4 * i + 0] = U.hh[0] * sc; qh[4 * i + 1] = U.hh[1] * sc;
            qh[4 * i + 2] = U.hh[2] * sc; qh[4 * i + 3] = U.hh[3] * sc;
        }
    }

    __syncthreads();

    auto score = [&](const unsigned short* kp) -> float {
        float s0 = 0.f, s1 = 0.f, s2 = 0.f, s3 = 0.f;
        #pragma unroll
        for (int c = 0; c < 8; ++c) {
            union { uint4 u; h2 hh[4]; } U;
            U.u = *(const uint4*)(kp + c * 8);
            s0 = DOT2(U.hh[0], qh[4 * c + 0], s0);
            s1 = DOT2(U.hh[1], qh[4 * c + 1], s1);
            s2 = DOT2(U.hh[2], qh[4 * c + 2], s2);
            s3 = DOT2(U.hh[3], qh[4 * c + 3], s3);
        }
        return (s0 + s1) + (s2 + s3);
    };

    h2 out2[32];
    #pragma unroll
    for (int i = 0; i < 32; ++i) out2[i] = (h2){ (_Float16)0.f, (_Float16)0.f };

    // ---- local phase: my 2 window keys w = 2ks, 2ks+1 (rows qloc+w) ----
    float pl0 = __expf(score(Kl + (qloc + 2 * ks + 0) * 72));
    float pl1 = __expf(score(Kl + (qloc + 2 * ks + 1) * 72));
    float den = pl0 + pl1;
    den += __shfl_xor(den, 1, 64);
    den += __shfl_xor(den, 2, 64);
    den += __shfl_xor(den, 4, 64);
    const float inv = 1.f / den;
    #pragma unroll
    for (int w = 0; w < 2; ++w) {
        const float pn = (w ? pl1 : pl0) * inv;
        h2 ph; ph.x = (_Float16)pn; ph.y = ph.x;
        const unsigned short* vp = Vl + (qloc + 2 * ks + w) * 72;
        #pragma unroll
        for (int c = 0; c < 8; ++c) {
            union { uint4 u; h2 hh[4]; } U;
            U.u = *(const uint4*)(vp + c * 8);
            out2[4 * c + 0] += ph * U.hh[0]; out2[4 * c + 1] += ph * U.hh[1];
            out2[4 * c + 2] += ph * U.hh[2]; out2[4 * c + 3] += ph * U.hh[3];
        }
    }

    // ---- global phase: my 16 keys g = ks*16 + i (fully unrolled) ----
    float pg[16];
    float deng = 0.f;
    #pragma unroll
    for (int i = 0; i < 16; ++i) {
        const int g = ks * 16 + i;
        const int row = ((g & 7) << 4) | (g >> 3);
        const float e = __expf(score(Kg + row * 72));
        pg[i] = e; deng += e;
    }
    deng += __shfl_xor(deng, 1, 64);
    deng += __shfl_xor(deng, 2, 64);
    deng += __shfl_xor(deng, 4, 64);
    const float invg = 1.f / deng;
    #pragma unroll
    for (int i = 0; i < 16; ++i) {
        const int g = ks * 16 + i;
        const int row = ((g & 7) << 4) | (g >> 3);
        const float pn = pg[i] * invg;
        h2 ph; ph.x = (_Float16)pn; ph.y = ph.x;
        const unsigned short* vp = Vg + row * 72;
        #pragma unroll
        for (int c = 0; c < 8; ++c) {
            union { uint4 u; h2 hh[4]; } U;
            U.u = *(const uint4*)(vp + c * 8);
            out2[4 * c + 0] += ph * U.hh[0]; out2[4 * c + 1] += ph * U.hh[1];
            out2[4 * c + 2] += ph * U.hh[2]; out2[4 * c + 3] += ph * U.hh[3];
        }
    }

    // ---- butterfly reduce-scatter over the 8 ks lanes ----
    h2 a[16];
    {
        const bool hi = (ks & 4) != 0;
        #pragma unroll
        for (int i = 0; i < 16; ++i) {
            h2 snd  = hi ? out2[i] : out2[i + 16];
            h2 rcv  = shfl_h2(snd, 4);
            a[i] = (hi ? out2[i + 16] : out2[i]) + rcv;
        }
    }
    h2 bb[8];
    {
        const bool hi = (ks & 2) != 0;
        #pragma unroll
        for (int i = 0; i < 8; ++i) {
            h2 snd  = hi ? a[i] : a[i + 8];
            h2 rcv  = shfl_h2(snd, 2);
            bb[i] = (hi ? a[i + 8] : a[i]) + rcv;
        }
    }
    h2 c4[4];
    {
        const bool hi = (ks & 1) != 0;
        #pragma unroll
        for (int i = 0; i < 4; ++i) {
            h2 snd  = hi ? bb[i] : bb[i + 4];
            h2 rcv  = shfl_h2(snd, 1);
            c4[i] = (hi ? bb[i + 4] : bb[i]) + rcv;
        }
    }

    // ---- write my 8 dims as bf16 (fixed registers, no dynamic index) ----
    {
        unsigned int pk[4];
        #pragma unroll
        for (int j = 0; j < 4; ++j)
            pk[j] = (unsigned int)f2bf((float)c4[j].x) | ((unsigned int)f2bf((float)c4[j].y) << 16);
        uint4 st = { pk[0], pk[1], pk[2], pk[3] };
        *(uint4*)(attn_out + (size_t)(b * TT + tq) * DD + h * HD + ks * 8) = st;
    }
}

extern "C" void kernel_launch(void* const* d_in, const int* in_sizes, int n_in,
                              void* d_out, int out_size, void* d_ws, size_t ws_size,
                              hipStream_t stream) {
    const float* x      = (const float*)d_in[0];  // (B*T) x D fp32
    const float* w_qkv  = (const float*)d_in[1];  // D x 3D fp32
    const float* w_proj = (const float*)d_in[2];  // D x D fp32
    const float* b_proj = (const float*)d_in[3];  // D fp32

    // ws layout (41.94 MB total):
    //   qkv fp16 (4096x3072)      : 25.166 MB
    //   xb/attnb bf16 (4096x1024) :  8.389 MB  (aliased: xb dead after gemm1)
    //   wqkvT bf16 (3072x1024)    :  6.291 MB
    //   wprojT bf16 (1024x1024)   :  2.097 MB
    char* ws = (char*)d_ws;
    unsigned short* qkv    = (unsigned short*)ws;
    unsigned short* xb     = (unsigned short*)(ws + 25165824);
    unsigned short* attnb  = xb;
    unsigned short* wqkvT  = (unsigned short*)(ws + 25165824 + 8388608);
    unsigned short* wprojT = (unsigned short*)(ws + 25165824 + 8388608 + 6291456);
    float* out = (float*)d_out;

    // 0) fused pre-pass: x -> bf16; both weights -> transposed bf16
    prepass_kernel<<<3072, 256, 0, stream>>>(x, w_qkv, w_proj, xb, wqkvT, wprojT);

    // 1) qkv = x @ w_qkv  (bf16 MFMA, fp16 out), 128x128 tiles, 768 blocks
    gemm_kernel<0, 128><<<dim3(3072 / 128, 4096 / 128), 256, 0, stream>>>(
        xb, wqkvT, qkv, nullptr, 4096, 3072, 1024);

    // 2) sparse attention (local window + global strided), bf16 out
    attn_kernel<<<dim3(BB * HH * (TT / 32)), 256, 0, stream>>>(qkv, attnb);

    // 3) out = attnb @ w_proj + b_proj, fp32 out — 128x64 tiles, 512 blocks
    gemm_kernel<1, 64><<<dim3(1024 / 64, 4096 / 128), 256, 0, stream>>>(
        attnb, wprojT, out, b_proj, 4096, 1024, 1024);
}